// Round 3
// baseline (10106.321 us; speedup 1.0000x reference)
//
#include <hip/hip_runtime.h>
#include <stdint.h>

typedef __attribute__((ext_vector_type(8))) short bf16x8;
typedef __attribute__((ext_vector_type(4))) float f32x4;
typedef __attribute__((ext_vector_type(4))) unsigned int u32x4;

__device__ __forceinline__ unsigned short f2bf(float f) {
  unsigned int u = __float_as_uint(f);
  return (unsigned short)((u + 0x7fffu + ((u >> 16) & 1u)) >> 16);  // RNE
}

template<int AUX>
__device__ __forceinline__ void gload16(const void* g, void* l) {
  if constexpr (AUX == 2)
    __builtin_amdgcn_global_load_lds((const __attribute__((address_space(1))) void*)g,
                                     (__attribute__((address_space(3))) void*)l, 16, 0, 2);
  else
    __builtin_amdgcn_global_load_lds((const __attribute__((address_space(1))) void*)g,
                                     (__attribute__((address_space(3))) void*)l, 16, 0, 0);
}

// ---------------------------------------------------------------- zero
__global__ void zero_k(u32x4* __restrict__ p, int n16) {
  int i = blockIdx.x * blockDim.x + threadIdx.x;
  int stride = gridDim.x * blockDim.x;
  u32x4 z = {0u, 0u, 0u, 0u};
  for (; i < n16; i += stride) p[i] = z;
}

// ------------------------------------------- fp32 NHWC -> padded bf16 NHWC
__global__ void conv_in_k(const float* __restrict__ x, unsigned short* __restrict__ dst,
                          int H, int total) {
  int idx = blockIdx.x * 256 + threadIdx.x;
  if (idx >= total) return;
  const int W = H, Hp = H + 2, Wp = H + 2;
  int c8 = idx & 31;
  int rest = idx >> 5;
  int xp = rest % Wp;
  int r2 = rest / Wp;
  int yp = r2 % Hp;
  int n = r2 / Hp;
  u32x4 o = {0u, 0u, 0u, 0u};
  int iy = yp - 1, ix = xp - 1;
  if ((unsigned)iy < (unsigned)H && (unsigned)ix < (unsigned)W) {
    const float* s = x + ((long)((n * H + iy) * W + ix) * 256 + c8 * 8);
    float4 a = *(const float4*)s;
    float4 b = *(const float4*)(s + 4);
    o.x = f2bf(a.x) | ((unsigned)f2bf(a.y) << 16);
    o.y = f2bf(a.z) | ((unsigned)f2bf(a.w) << 16);
    o.z = f2bf(b.x) | ((unsigned)f2bf(b.y) << 16);
    o.w = f2bf(b.z) | ((unsigned)f2bf(b.w) << 16);
  }
  *(u32x4*)(dst + (long)idx * 8) = o;
}

// -------- HWIO fp32 -> bf16 MFMA-fragment layout (same as R2, verified)
__global__ void conv_w_k(const float* __restrict__ w, unsigned short* __restrict__ wTf,
                         int CoutReal, int NB, int totalChunks) {
  int f = blockIdx.x * 256 + threadIdx.x;
  if (f >= totalChunks) return;
  int l = f & 63;
  int t2 = f >> 6;
  int ks = t2 & 1;
  int t3 = t2 >> 1;
  int jg = t3 % NB;
  int stage = t3 / NB;
  int col = jg * 16 + (l & 15);
  int kbase = stage * 64 + ks * 32 + ((l >> 4) << 3);
  u32x4 o = {0u, 0u, 0u, 0u};
  if (col < CoutReal) {
    unsigned short v[8];
#pragma unroll
    for (int e = 0; e < 8; ++e)
      v[e] = f2bf(w[(long)(kbase + e) * CoutReal + col]);
    o.x = v[0] | ((unsigned)v[1] << 16);
    o.y = v[2] | ((unsigned)v[3] << 16);
    o.z = v[4] | ((unsigned)v[5] << 16);
    o.w = v[6] | ((unsigned)v[7] << 16);
  }
  *(u32x4*)(wTf + (long)f * 8) = o;
}

// ---------------------------------------------------------------- conv 3x3
// Block = 8x16 pixel tile (128 px) x NF*64 couts. 4 waves, each 128px x NF*16 co.
// A: LDS halo [10][18][64ch] per cc-slice, staged once w/ NT hint, XOR-swizzled
// via pre-swizzled global src. B: register fragments from L2, 1-tap prefetch.
template<int NF, bool FINAL, int AUX>
__global__ __launch_bounds__(256, 2)
void conv3x3_k(const unsigned short* __restrict__ src,
               const unsigned short* __restrict__ wTf,
               const float* __restrict__ bias,
               unsigned short* __restrict__ dstAct,
               float* __restrict__ dstOut,
               int H, int CoutReal, int NB, int ntN)
{
  __shared__ char smem[65536];        // A halo 24KB; epilogue C-stage 64KB (reused)
  const int tid = threadIdx.x;
  const int W = H, Hp = H + 2, RL = H + 2;
  int bx = blockIdx.x, tn, tc;
  if (ntN == 3) { tn = bx % 3; tc = bx / 3; } else { tn = 0; tc = bx; }
  const int tileN = tn * (NF * 64);
  const int y0 = blockIdx.y * 8;
  const int x0 = tc * 16;
  const int n_img = blockIdx.z;

  // A staging: 180 halo rows x 128B = 1440 chunks; 6 iters x 256 thr (tail dup)
  int srcOff[6];
#pragma unroll
  for (int j = 0; j < 6; ++j) {
    int q = j * 256 + tid;
    int hr = q >> 3, c = q & 7;
    if (hr >= 180) hr = 0;
    int hy = hr / 18, hx = hr - hy * 18;
    int lch = c ^ (hr & 7);
    srcOff[j] = ((n_img * Hp + y0 + hy) * RL + x0 + hx) * 256 + lch * 8;
  }

  const int lane = tid & 63;
  const int wv = tid >> 6;
  const int l15 = lane & 15;
  const int k8 = lane >> 4;
  const int jgBase = (tileN >> 4) + wv * NF;
  const unsigned short* wBp = wTf + jgBase * 1024 + lane * 8;
  const int stageStride = NB << 10;

  f32x4 acc[8][NF];
#pragma unroll
  for (int m = 0; m < 8; ++m)
#pragma unroll
    for (int n = 0; n < NF; ++n)
      acc[m][n] = (f32x4){0.f, 0.f, 0.f, 0.f};

  auto loadB = [&](bf16x8 (&dst)[NF][2], int stage) {
    const unsigned short* bp = wBp + stage * stageStride;
#pragma unroll
    for (int n = 0; n < NF; ++n)
#pragma unroll
      for (int ks = 0; ks < 2; ++ks)
        dst[n][ks] = *(const bf16x8*)(bp + n * 1024 + ks * 512);
  };

  bf16x8 bnx[NF][2];
  loadB(bnx, 0);                      // stage = tap*4+cc = 0

  for (int cc = 0; cc < 4; ++cc) {
    if (cc) __syncthreads();          // prev slice reads done
#pragma unroll
    for (int j = 0; j < 6; ++j)
      gload16<AUX>(src + srcOff[j] + cc * 64, smem + j * 4096 + tid * 16);
    __syncthreads();                  // drain staging
#pragma unroll
    for (int tap = 0; tap < 9; ++tap) {
      const int ky = tap / 3, kx = tap - ky * 3;
      bf16x8 bcur[NF][2];
#pragma unroll
      for (int n = 0; n < NF; ++n) {
        bcur[n][0] = bnx[n][0];
        bcur[n][1] = bnx[n][1];
      }
      const int nst = (tap < 8) ? ((tap + 1) * 4 + cc) : (cc < 3 ? (cc + 1) : 35);
      loadB(bnx, nst);                // prefetch next stage (L2 hit)
#pragma unroll
      for (int m = 0; m < 8; ++m) {
        const int rA = (m + ky) * 18 + l15 + kx;
        const int a0 = rA * 128 + ((k8 ^ (rA & 7)) << 4);
        bf16x8 av0 = *(const bf16x8*)(smem + a0);
        bf16x8 av1 = *(const bf16x8*)(smem + (a0 ^ 64));
#pragma unroll
        for (int n = 0; n < NF; ++n) {
          acc[m][n] = __builtin_amdgcn_mfma_f32_16x16x32_bf16(av0, bcur[n][0], acc[m][n], 0, 0, 0);
          acc[m][n] = __builtin_amdgcn_mfma_f32_16x16x32_bf16(av1, bcur[n][1], acc[m][n], 0, 0, 0);
        }
      }
    }
  }

  // Epilogue. C/D frag: col=l15 (cout), M-idx=k8*4+r (pixel col within 16).
  if constexpr (FINAL) {
    float* cf = (float*)smem;
    constexpr int NHALF = (NF == 4) ? 2 : 1;
#pragma unroll
    for (int h = 0; h < NHALF; ++h) {
      __syncthreads();
      const bool mine = (NF == 2) || ((wv >> 1) == h);
      if (mine) {
#pragma unroll
        for (int n = 0; n < NF; ++n) {
          const int colh = (NF == 2 ? wv * 32 : (wv & 1) * 64) + n * 16 + l15;
          const int colG = tileN + h * 128 + colh;
          const float bvl = (colG < CoutReal) ? bias[colG] : 0.f;
#pragma unroll
          for (int m = 0; m < 8; ++m)
#pragma unroll
            for (int r = 0; r < 4; ++r) {
              const int px = m * 16 + (k8 << 2) + r;
              const int cphys = ((colh >> 2) + 2 * ((px >> 2) & 3)) & 31;
              cf[px * 128 + cphys * 4 + (colh & 3)] = acc[m][n][r] + bvl;
            }
        }
      }
      __syncthreads();
#pragma unroll
      for (int it = 0; it < 16; ++it) {
        const int chunk = it * 256 + tid;
        const int px = chunk >> 5, c4 = chunk & 31;
        const int colG = tileN + h * 128 + c4 * 4;
        if (colG < CoutReal) {
          const int cphys = (c4 + 2 * ((px >> 2) & 3)) & 31;
          u32x4 v = *(const u32x4*)(cf + px * 128 + cphys * 4);
          const int y = y0 + (px >> 4), x = x0 + (px & 15);
          const long p = ((long)n_img * H + y) * W + x;
          *(u32x4*)(dstOut + p * CoutReal + colG) = v;
        }
      }
    }
  } else {
    unsigned short* cb = (unsigned short*)smem;
    __syncthreads();
#pragma unroll
    for (int n = 0; n < NF; ++n) {
      const int col = wv * (NF * 16) + n * 16 + l15;
      const float bvl = bias[col];
#pragma unroll
      for (int m = 0; m < 8; ++m)
#pragma unroll
        for (int r = 0; r < 4; ++r) {
          const int px = m * 16 + (k8 << 2) + r;
          const int cphys = ((col >> 3) + 2 * ((px >> 2) & 3)) & 31;
          cb[px * 256 + cphys * 8 + (col & 7)] = f2bf(fmaxf(acc[m][n][r] + bvl, 0.f));
        }
    }
    __syncthreads();
#pragma unroll
    for (int it = 0; it < 16; ++it) {
      const int chunk = it * 256 + tid;
      const int px = chunk >> 5, c8 = chunk & 31;
      const int cphys = (c8 + 2 * ((px >> 2) & 3)) & 31;
      u32x4 v = *(const u32x4*)(cb + px * 256 + cphys * 8);
      const int y = y0 + (px >> 4), x = x0 + (px & 15);
      const long o = ((long)(n_img * Hp + y + 1) * RL + x + 1) * 256 + c8 * 8;
      *(u32x4*)(dstAct + o) = v;
    }
  }
}

// ---------------------------------------------------------------- host
static void run_branch(const unsigned short* A, unsigned short* Am, unsigned short* B,
                       const unsigned short* wT, const float* bias,
                       const unsigned short* wTout, const float* biasOut,
                       bool cls, float* out, int H, hipStream_t stream) {
  dim3 blk(256);
  dim3 gi(H / 16, H / 8, 8);
  conv3x3_k<4, false, 2><<<gi, blk, 0, stream>>>(A,  wT + 0L * 589824, bias + 0,   B,  nullptr, H, 256, 16, 1);
  conv3x3_k<4, false, 2><<<gi, blk, 0, stream>>>(B,  wT + 1L * 589824, bias + 256, Am, nullptr, H, 256, 16, 1);
  conv3x3_k<4, false, 2><<<gi, blk, 0, stream>>>(Am, wT + 2L * 589824, bias + 512, B,  nullptr, H, 256, 16, 1);
  conv3x3_k<4, false, 2><<<gi, blk, 0, stream>>>(B,  wT + 3L * 589824, bias + 768, Am, nullptr, H, 256, 16, 1);
  if (cls) {
    dim3 gf(3 * H / 16, H / 8, 8);
    conv3x3_k<4, true, 2><<<gf, blk, 0, stream>>>(Am, wTout, biasOut, nullptr, out, H, 720, 48, 3);
  } else {
    dim3 gf(H / 16, H / 8, 8);
    conv3x3_k<2, true, 2><<<gf, blk, 0, stream>>>(Am, wTout, biasOut, nullptr, out, H, 36, 8, 1);
  }
}

extern "C" void kernel_launch(void* const* d_in, const int* in_sizes, int n_in,
                              void* d_out, int out_size, void* d_ws, size_t ws_size,
                              hipStream_t stream) {
  const float* x[3] = {(const float*)d_in[0], (const float*)d_in[1], (const float*)d_in[2]};
  const float* cls_w      = (const float*)d_in[3];
  const float* cls_b      = (const float*)d_in[4];
  const float* bbox_w     = (const float*)d_in[5];
  const float* bbox_b     = (const float*)d_in[6];
  const float* cls_out_w  = (const float*)d_in[7];
  const float* cls_out_b  = (const float*)d_in[8];
  const float* bbox_out_w = (const float*)d_in[9];
  const float* bbox_out_b = (const float*)d_in[10];
  float* out = (float*)d_out;

  char* ws = (char*)d_ws;
  unsigned short* bufA = (unsigned short*)ws;
  unsigned short* bufB = (unsigned short*)(ws + 69222400);
  unsigned short* wt   = (unsigned short*)(ws + 138444800);
  unsigned short* wT_cls      = wt;
  unsigned short* wT_bbox     = wt + 4L * 589824;
  unsigned short* wT_cls_out  = wt + 8L * 589824;         // 48 jg * 36 st * 2 * 512
  unsigned short* wT_bbox_out = wT_cls_out + 2211840;     // 8 jg

  for (int i = 0; i < 4; ++i) {
    conv_w_k<<<288, 256, 0, stream>>>(cls_w  + (long)i * 589824, wT_cls  + (long)i * 589824, 256, 16, 73728);
    conv_w_k<<<288, 256, 0, stream>>>(bbox_w + (long)i * 589824, wT_bbox + (long)i * 589824, 256, 16, 73728);
  }
  conv_w_k<<<864, 256, 0, stream>>>(cls_out_w,  wT_cls_out,  720, 48, 221184);
  conv_w_k<<<144, 256, 0, stream>>>(bbox_out_w, wT_bbox_out, 36, 8, 36864);

  const int  Hs[3]   = {128, 64, 32};
  const long clsOff[3] = {0L, 94371840L, 117964800L};
  const long boxOff[3] = {123863040L, 128581632L, 129761280L};

  for (int lv = 0; lv < 3; ++lv) {
    const int H = Hs[lv], Hp = H + 2;
    const int paddedElems = 8 * Hp * Hp * 256;
    const int totalConv = 8 * Hp * Hp * 32;

    zero_k<<<2048, 256, 0, stream>>>((u32x4*)bufB, paddedElems / 8);

    conv_in_k<<<(totalConv + 255) / 256, 256, 0, stream>>>(x[lv], bufA, H, totalConv);
    run_branch(bufA, bufA, bufB, wT_cls, cls_b, wT_cls_out, cls_out_b,
               true, out + clsOff[lv], H, stream);

    conv_in_k<<<(totalConv + 255) / 256, 256, 0, stream>>>(x[lv], bufA, H, totalConv);
    run_branch(bufA, bufA, bufB, wT_bbox, bbox_b, wT_bbox_out, bbox_out_b,
               false, out + boxOff[lv], H, stream);
  }
}

// Round 4
// 3980.508 us; speedup vs baseline: 2.5390x; 2.5390x over previous
//
#include <hip/hip_runtime.h>
#include <stdint.h>

typedef __attribute__((ext_vector_type(8))) short bf16x8;
typedef __attribute__((ext_vector_type(4))) float f32x4;
typedef __attribute__((ext_vector_type(4))) unsigned int u32x4;

__device__ __forceinline__ unsigned short f2bf(float f) {
  unsigned int u = __float_as_uint(f);
  return (unsigned short)((u + 0x7fffu + ((u >> 16) & 1u)) >> 16);  // RNE
}

__device__ __forceinline__ void gload16(const void* g, void* l) {
  __builtin_amdgcn_global_load_lds((const __attribute__((address_space(1))) void*)g,
                                   (__attribute__((address_space(3))) void*)l, 16, 0, 0);
}

// ---------------------------------------------------------------- zero
__global__ void zero_k(u32x4* __restrict__ p, int n16) {
  int i = blockIdx.x * blockDim.x + threadIdx.x;
  int stride = gridDim.x * blockDim.x;
  u32x4 z = {0u, 0u, 0u, 0u};
  for (; i < n16; i += stride) p[i] = z;
}

// ------------------------------------------- fp32 NHWC -> padded bf16 NHWC
__global__ void conv_in_k(const float* __restrict__ x, unsigned short* __restrict__ dst,
                          int H, int total) {
  int idx = blockIdx.x * 256 + threadIdx.x;
  if (idx >= total) return;
  const int W = H, Hp = H + 2, Wp = H + 2;
  int c8 = idx & 31;
  int rest = idx >> 5;
  int xp = rest % Wp;
  int r2 = rest / Wp;
  int yp = r2 % Hp;
  int n = r2 / Hp;
  u32x4 o = {0u, 0u, 0u, 0u};
  int iy = yp - 1, ix = xp - 1;
  if ((unsigned)iy < (unsigned)H && (unsigned)ix < (unsigned)W) {
    const float* s = x + ((long)((n * H + iy) * W + ix) * 256 + c8 * 8);
    float4 a = *(const float4*)s;
    float4 b = *(const float4*)(s + 4);
    o.x = f2bf(a.x) | ((unsigned)f2bf(a.y) << 16);
    o.y = f2bf(a.z) | ((unsigned)f2bf(a.w) << 16);
    o.z = f2bf(b.x) | ((unsigned)f2bf(b.y) << 16);
    o.w = f2bf(b.z) | ((unsigned)f2bf(b.w) << 16);
  }
  *(u32x4*)(dst + (long)idx * 8) = o;
}

// -------- HWIO fp32 -> bf16 MFMA-fragment layout (verified R2/R3)
// chunk f: l=f&63; ks=(f>>6)&1; jg=(f>>7)%NB; stage=(f>>7)/NB  (stage = tap*4+cc)
__global__ void conv_w_k(const float* __restrict__ w, unsigned short* __restrict__ wTf,
                         int CoutReal, int NB, int totalChunks) {
  int f = blockIdx.x * 256 + threadIdx.x;
  if (f >= totalChunks) return;
  int l = f & 63;
  int t2 = f >> 6;
  int ks = t2 & 1;
  int t3 = t2 >> 1;
  int jg = t3 % NB;
  int stage = t3 / NB;
  int col = jg * 16 + (l & 15);
  int kbase = stage * 64 + ks * 32 + ((l >> 4) << 3);
  u32x4 o = {0u, 0u, 0u, 0u};
  if (col < CoutReal) {
    unsigned short v[8];
#pragma unroll
    for (int e = 0; e < 8; ++e)
      v[e] = f2bf(w[(long)(kbase + e) * CoutReal + col]);
    o.x = v[0] | ((unsigned)v[1] << 16);
    o.y = v[2] | ((unsigned)v[3] << 16);
    o.z = v[4] | ((unsigned)v[5] << 16);
    o.w = v[6] | ((unsigned)v[7] << 16);
  }
  *(u32x4*)(wTf + (long)f * 8) = o;
}

// ---------------------------------------------------------------- conv 3x3
// Tile 128 px (1D, row-major) x 128 cout. 4 waves: wave = 64 px x 64 co.
// acc[4][4]=64 VGPR. A: LDS halo [(ROWS+2)*RL rows][64ch] staged once per cc
// (global_load_lds, source-side XOR swizzle). B: register frags from L2
// (8x 1KB coalesced per wave per tap). XCD-chunked pixel-tile swizzle.
template<bool FINAL>
__global__ __launch_bounds__(256) __attribute__((amdgpu_waves_per_eu(3, 4)))
void conv3x3_k(const unsigned short* __restrict__ src,
               const unsigned short* __restrict__ wTf,
               const float* __restrict__ bias,
               unsigned short* __restrict__ dstAct,
               float* __restrict__ dstOut,
               int H, int lW, int lHW, int CoutReal, int NB,
               int NROWS, int NITER, unsigned magicRL)
{
  __shared__ char smem[53248];
  const int tid = threadIdx.x;
  const int W = H, Hp = H + 2, RL = H + 2;
  const int nx = gridDim.x;
  const int bx = blockIdx.x;
  const int wg = (bx & 7) * (nx >> 3) + (bx >> 3);   // XCD-chunked swizzle
  const int tileM = wg * 128;
  const int tileN = blockIdx.y * 128;
  const int n_img = tileM >> lHW;
  const int ystart = (tileM >> lW) & (H - 1);

  const int lane = tid & 63;
  const int wv = tid >> 6;
  const int l15 = lane & 15;
  const int k8 = lane >> 4;
  const int pxW = (wv & 1) * 64;
  const int jgBase = (tileN >> 4) + (wv >> 1) * 4;

  int rBase[4];
#pragma unroll
  for (int m = 0; m < 4; ++m) {
    const int px = pxW + m * 16 + l15;
    rBase[m] = (px >> lW) * RL + (px & (W - 1));
  }

  f32x4 acc[4][4];
#pragma unroll
  for (int m = 0; m < 4; ++m)
#pragma unroll
    for (int n = 0; n < 4; ++n)
      acc[m][n] = (f32x4){0.f, 0.f, 0.f, 0.f};

  const size_t aRowBase = (size_t)(n_img * Hp + ystart) * RL;

  for (int cc = 0; cc < 4; ++cc) {
    if (cc) __syncthreads();               // prev slice reads done
    for (int j = 0; j < NITER; ++j) {
      int q = j * 256 + tid;
      int r = q >> 3, c = q & 7;
      if (r >= NROWS) r = 0;               // tail dup, harmless
      int ry = (int)(((unsigned long long)(unsigned)r * magicRL) >> 32);
      int ix = r - ry * RL;
      int lch = c ^ (r & 7);               // inverse swizzle on global source
      gload16(src + (aRowBase + (size_t)ry * RL + ix) * 256 + lch * 8 + cc * 64,
              smem + q * 16);
    }
    __syncthreads();                       // drain staging
#pragma unroll
    for (int tap = 0; tap < 9; ++tap) {
      const int ky = tap / 3, kx = tap - ky * 3;
      const unsigned short* bbase =
          wTf + ((size_t)((tap * 4 + cc) * NB + jgBase)) * 1024 + lane * 8;
      bf16x8 bf_[4][2];
#pragma unroll
      for (int n = 0; n < 4; ++n)
#pragma unroll
        for (int ks = 0; ks < 2; ++ks)
          bf_[n][ks] = *(const bf16x8*)(bbase + n * 1024 + ks * 512);
#pragma unroll
      for (int m = 0; m < 4; ++m) {
        const int rA = rBase[m] + ky * RL + kx;
        const int a0 = rA * 128 + ((k8 ^ (rA & 7)) << 4);
        bf16x8 av0 = *(const bf16x8*)(smem + a0);
        bf16x8 av1 = *(const bf16x8*)(smem + (a0 ^ 64));
#pragma unroll
        for (int n = 0; n < 4; ++n) {
          acc[m][n] = __builtin_amdgcn_mfma_f32_16x16x32_bf16(av0, bf_[n][0], acc[m][n], 0, 0, 0);
          acc[m][n] = __builtin_amdgcn_mfma_f32_16x16x32_bf16(av1, bf_[n][1], acc[m][n], 0, 0, 0);
        }
      }
    }
  }

  // ---- epilogue. C/D frag: col=l15, px_in_frag=k8*4+r (verified layout).
  if constexpr (FINAL) {
    float* cf = (float*)smem;              // [64 px][128 co] fp32 = 32KB per half
#pragma unroll
    for (int h = 0; h < 2; ++h) {
      __syncthreads();
      if ((wv & 1) == h) {
#pragma unroll
        for (int n = 0; n < 4; ++n) {
          const int col = (wv >> 1) * 64 + n * 16 + l15;
          const int colG = tileN + col;
          const float bvl = (colG < CoutReal) ? bias[colG] : 0.f;
          const int c32 = col >> 2;
#pragma unroll
          for (int m = 0; m < 4; ++m)
#pragma unroll
            for (int r = 0; r < 4; ++r) {
              const int pxl = m * 16 + (k8 << 2) + r;       // 0..63
              const int phys = (c32 + (k8 & 1) * 4) & 31;   // 2-way max
              cf[pxl * 128 + phys * 4 + (col & 3)] = acc[m][n][r] + bvl;
            }
        }
      }
      __syncthreads();
#pragma unroll
      for (int it = 0; it < 8; ++it) {
        const int q = it * 256 + tid;
        const int pxl = q >> 5, c32 = q & 31;
        const int colG = tileN + c32 * 4;
        if (colG < CoutReal) {
          const int phys = (c32 + ((pxl >> 2) & 1) * 4) & 31;
          u32x4 v = *(const u32x4*)(cf + pxl * 128 + phys * 4);
          const int px = h * 64 + pxl;
          const int y = ystart + (px >> lW), x = px & (W - 1);
          const size_t p = ((size_t)(n_img * H + y)) * W + x;
          *(u32x4*)(dstOut + p * CoutReal + colG) = v;
        }
      }
    }
  } else {
    __syncthreads();                       // smem free; reuse as C tile
    unsigned short* cb = (unsigned short*)smem;   // [128 px][128 co] bf16 = 32KB
#pragma unroll
    for (int n = 0; n < 4; ++n) {
      const int col = (wv >> 1) * 64 + n * 16 + l15;
      const float bvl = bias[tileN + col];
      const int c16 = col >> 3;
#pragma unroll
      for (int m = 0; m < 4; ++m)
#pragma unroll
        for (int r = 0; r < 4; ++r) {
          const int px = pxW + m * 16 + (k8 << 2) + r;
          const int phys = (c16 + k8 * 2) & 15;             // conflict-free
          cb[px * 128 + phys * 8 + (col & 7)] = f2bf(fmaxf(acc[m][n][r] + bvl, 0.f));
        }
    }
    __syncthreads();
#pragma unroll
    for (int it = 0; it < 8; ++it) {
      const int q = it * 256 + tid;
      const int px = q >> 4, c16 = q & 15;
      const int phys = (c16 + ((px >> 2) & 3) * 2) & 15;
      u32x4 v = *(const u32x4*)(cb + px * 128 + phys * 8);
      const int y = ystart + (px >> lW), x = px & (W - 1);
      const size_t o = ((size_t)(n_img * Hp + y + 1) * RL + x + 1) * 256 + tileN + c16 * 8;
      *(u32x4*)(dstAct + o) = v;
    }
  }
}

// ---------------------------------------------------------------- host
struct LvlP { int H, lW, lHW, NROWS, NITER; unsigned magic; };

static void run_branch(const unsigned short* A, unsigned short* Am, unsigned short* B,
                       const unsigned short* wT, const float* bias,
                       const unsigned short* wTout, const float* biasOut,
                       int CoutReal, int outPhases, int NBf, float* out,
                       const LvlP& L, hipStream_t stream) {
  dim3 blk(256);
  const int nx = 8 * L.H * L.H / 128;
  dim3 g1(nx, 2);
  conv3x3_k<false><<<g1, blk, 0, stream>>>(A,  wT + 0L * 589824, bias + 0,   B,  nullptr, L.H, L.lW, L.lHW, 256, 16, L.NROWS, L.NITER, L.magic);
  conv3x3_k<false><<<g1, blk, 0, stream>>>(B,  wT + 1L * 589824, bias + 256, Am, nullptr, L.H, L.lW, L.lHW, 256, 16, L.NROWS, L.NITER, L.magic);
  conv3x3_k<false><<<g1, blk, 0, stream>>>(Am, wT + 2L * 589824, bias + 512, B,  nullptr, L.H, L.lW, L.lHW, 256, 16, L.NROWS, L.NITER, L.magic);
  conv3x3_k<false><<<g1, blk, 0, stream>>>(B,  wT + 3L * 589824, bias + 768, Am, nullptr, L.H, L.lW, L.lHW, 256, 16, L.NROWS, L.NITER, L.magic);
  dim3 g2(nx, outPhases);
  conv3x3_k<true><<<g2, blk, 0, stream>>>(Am, wTout, biasOut, nullptr, out, L.H, L.lW, L.lHW, CoutReal, NBf, L.NROWS, L.NITER, L.magic);
}

extern "C" void kernel_launch(void* const* d_in, const int* in_sizes, int n_in,
                              void* d_out, int out_size, void* d_ws, size_t ws_size,
                              hipStream_t stream) {
  const float* x[3] = {(const float*)d_in[0], (const float*)d_in[1], (const float*)d_in[2]};
  const float* cls_w      = (const float*)d_in[3];
  const float* cls_b      = (const float*)d_in[4];
  const float* bbox_w     = (const float*)d_in[5];
  const float* bbox_b     = (const float*)d_in[6];
  const float* cls_out_w  = (const float*)d_in[7];
  const float* cls_out_b  = (const float*)d_in[8];
  const float* bbox_out_w = (const float*)d_in[9];
  const float* bbox_out_b = (const float*)d_in[10];
  float* out = (float*)d_out;

  char* ws = (char*)d_ws;
  unsigned short* bufA = (unsigned short*)ws;
  unsigned short* bufB = (unsigned short*)(ws + 69222400);
  unsigned short* wt   = (unsigned short*)(ws + 138444800);
  unsigned short* wT_cls      = wt;
  unsigned short* wT_bbox     = wt + 4L * 589824;
  unsigned short* wT_cls_out  = wt + 8L * 589824;         // 36*48*2*512
  unsigned short* wT_bbox_out = wT_cls_out + 2211840;     // 36*8*2*512

  for (int i = 0; i < 4; ++i) {
    conv_w_k<<<288, 256, 0, stream>>>(cls_w  + (long)i * 589824, wT_cls  + (long)i * 589824, 256, 16, 73728);
    conv_w_k<<<288, 256, 0, stream>>>(bbox_w + (long)i * 589824, wT_bbox + (long)i * 589824, 256, 16, 73728);
  }
  conv_w_k<<<864, 256, 0, stream>>>(cls_out_w,  wT_cls_out,  720, 48, 221184);
  conv_w_k<<<144, 256, 0, stream>>>(bbox_out_w, wT_bbox_out, 36, 8, 36864);

  const long clsOff[3] = {0L, 94371840L, 117964800L};
  const long boxOff[3] = {123863040L, 128581632L, 129761280L};
  LvlP Ls[3];
  const int Hs[3] = {128, 64, 32};
  const int lWs[3] = {7, 6, 5};
  const int lHWs[3] = {14, 12, 10};
  for (int lv = 0; lv < 3; ++lv) {
    const int H = Hs[lv], RL = H + 2;
    const int ROWS = 128 >> lWs[lv];
    const int NROWS = (ROWS + 2) * RL;
    Ls[lv] = {H, lWs[lv], lHWs[lv], NROWS, (NROWS + 31) / 32,
              (unsigned)((0x100000000ULL + RL - 1) / RL)};
  }

  for (int lv = 0; lv < 3; ++lv) {
    const int H = Hs[lv], Hp = H + 2;
    const int paddedElems = 8 * Hp * Hp * 256;
    const int totalConv = 8 * Hp * Hp * 32;

    zero_k<<<2048, 256, 0, stream>>>((u32x4*)bufB, paddedElems / 8);

    conv_in_k<<<(totalConv + 255) / 256, 256, 0, stream>>>(x[lv], bufA, H, totalConv);
    run_branch(bufA, bufA, bufB, wT_cls, cls_b, wT_cls_out, cls_out_b,
               720, 6, 48, out + clsOff[lv], Ls[lv], stream);

    conv_in_k<<<(totalConv + 255) / 256, 256, 0, stream>>>(x[lv], bufA, H, totalConv);
    run_branch(bufA, bufA, bufB, wT_bbox, bbox_b, wT_bbox_out, bbox_out_b,
               36, 1, 8, out + boxOff[lv], Ls[lv], stream);
  }
}

// Round 5
// 2584.573 us; speedup vs baseline: 3.9102x; 1.5401x over previous
//
#include <hip/hip_runtime.h>
#include <stdint.h>

typedef __attribute__((ext_vector_type(8))) short bf16x8;
typedef __attribute__((ext_vector_type(4))) float f32x4;
typedef __attribute__((ext_vector_type(4))) unsigned int u32x4;

__device__ __forceinline__ unsigned short f2bf(float f) {
  unsigned int u = __float_as_uint(f);
  return (unsigned short)((u + 0x7fffu + ((u >> 16) & 1u)) >> 16);  // RNE
}

__device__ __forceinline__ void gload16(const void* g, void* l) {
  __builtin_amdgcn_global_load_lds((const __attribute__((address_space(1))) void*)g,
                                   (__attribute__((address_space(3))) void*)l, 16, 0, 0);
}

// ---------------------------------------------------------------- zero
__global__ void zero_k(u32x4* __restrict__ p, int n16) {
  int i = blockIdx.x * blockDim.x + threadIdx.x;
  int stride = gridDim.x * blockDim.x;
  u32x4 z = {0u, 0u, 0u, 0u};
  for (; i < n16; i += stride) p[i] = z;
}

// ------------------------------------------- fp32 NHWC -> padded bf16 NHWC
__global__ void conv_in_k(const float* __restrict__ x, unsigned short* __restrict__ dst,
                          int H, int total) {
  int idx = blockIdx.x * 256 + threadIdx.x;
  if (idx >= total) return;
  const int W = H, Hp = H + 2, Wp = H + 2;
  int c8 = idx & 31;
  int rest = idx >> 5;
  int xp = rest % Wp;
  int r2 = rest / Wp;
  int yp = r2 % Hp;
  int n = r2 / Hp;
  u32x4 o = {0u, 0u, 0u, 0u};
  int iy = yp - 1, ix = xp - 1;
  if ((unsigned)iy < (unsigned)H && (unsigned)ix < (unsigned)W) {
    const float* s = x + ((long)((n * H + iy) * W + ix) * 256 + c8 * 8);
    float4 a = *(const float4*)s;
    float4 b = *(const float4*)(s + 4);
    o.x = f2bf(a.x) | ((unsigned)f2bf(a.y) << 16);
    o.y = f2bf(a.z) | ((unsigned)f2bf(a.w) << 16);
    o.z = f2bf(b.x) | ((unsigned)f2bf(b.y) << 16);
    o.w = f2bf(b.z) | ((unsigned)f2bf(b.w) << 16);
  }
  *(u32x4*)(dst + (long)idx * 8) = o;
}

// -------- HWIO fp32 -> bf16 MFMA-fragment layout (verified R2-R4)
// chunk f: l=f&63; ks=(f>>6)&1; jg=(f>>7)%NB; stage=(f>>7)/NB  (stage = tap*4+cc)
__global__ void conv_w_k(const float* __restrict__ w, unsigned short* __restrict__ wTf,
                         int CoutReal, int NB, int totalChunks) {
  int f = blockIdx.x * 256 + threadIdx.x;
  if (f >= totalChunks) return;
  int l = f & 63;
  int t2 = f >> 6;
  int ks = t2 & 1;
  int t3 = t2 >> 1;
  int jg = t3 % NB;
  int stage = t3 / NB;
  int col = jg * 16 + (l & 15);
  int kbase = stage * 64 + ks * 32 + ((l >> 4) << 3);
  u32x4 o = {0u, 0u, 0u, 0u};
  if (col < CoutReal) {
    unsigned short v[8];
#pragma unroll
    for (int e = 0; e < 8; ++e)
      v[e] = f2bf(w[(long)(kbase + e) * CoutReal + col]);
    o.x = v[0] | ((unsigned)v[1] << 16);
    o.y = v[2] | ((unsigned)v[3] << 16);
    o.z = v[4] | ((unsigned)v[5] << 16);
    o.w = v[6] | ((unsigned)v[7] << 16);
  }
  *(u32x4*)(wTf + (long)f * 8) = o;
}

// ---------------------------------------------------------------- conv 3x3
// Tile = 8x16 pixel patch (128 px) x 128 couts. 4 waves: wave = 64 px x 64 co,
// acc[4][4]=64 VGPR. A: LDS halo [10 y][18 x][64 ch] per cc-slice, staged once
// via global_load_lds (source-side XOR swizzle, linear LDS). B: register
// fragments from L2, next-tap prefetch (bcur/bnx). launch_bounds(256,2): no
// VGPR cap squeeze -> no spill.
template<bool FINAL>
__global__ __launch_bounds__(256, 2)
void conv3x3_k(const unsigned short* __restrict__ src,
               const unsigned short* __restrict__ wTf,
               const float* __restrict__ bias,
               unsigned short* __restrict__ dstAct,
               float* __restrict__ dstOut,
               int H, int lntx, int lnty, int CoutReal, int NB)
{
  __shared__ char smem[32768];   // staging uses [0,24576); epilogue reuses [0,32768)
  const int tid = threadIdx.x;
  const int W = H, Hp = H + 2, RL = H + 2;
  const int np = gridDim.x;
  const int bx = blockIdx.x;
  const int t = (bx & 7) * (np >> 3) + (bx >> 3);      // XCD-chunked swizzle
  const int tx = (t & ((1 << lntx) - 1)) << 4;
  const int ty = ((t >> lntx) & ((1 << lnty) - 1)) << 3;
  const int n_img = t >> (lntx + lnty);
  const int tileN = blockIdx.y * 128;

  // A staging: 180 halo rows (10y x 18x) x 128 B = 1440 chunks; 6 x 256 thr
  int srcOff[6];
#pragma unroll
  for (int j = 0; j < 6; ++j) {
    int q = j * 256 + tid;
    int hr = q >> 3, c = q & 7;
    if (hr >= 180) hr = 0;                 // tail dup, written past read region
    int hy = hr / 18, hx = hr - hy * 18;
    int lch = c ^ (hr & 7);                // inverse swizzle on global source
    srcOff[j] = ((n_img * Hp + ty + hy) * RL + tx + hx) * 256 + lch * 8;
  }

  const int lane = tid & 63;
  const int wv = tid >> 6;
  const int l15 = lane & 15;
  const int k8 = lane >> 4;
  const int pxRow = (wv & 1) * 4;          // wave's first pixel row (of 8)
  const int jgBase = (tileN >> 4) + (wv >> 1) * 4;
  const unsigned short* wBp = wTf + (size_t)jgBase * 1024 + lane * 8;
  const size_t stageStride = (size_t)NB << 10;

  int rBase[4];
#pragma unroll
  for (int m = 0; m < 4; ++m)
    rBase[m] = (pxRow + m) * 18 + l15;

  f32x4 acc[4][4];
#pragma unroll
  for (int m = 0; m < 4; ++m)
#pragma unroll
    for (int n = 0; n < 4; ++n)
      acc[m][n] = (f32x4){0.f, 0.f, 0.f, 0.f};

  auto loadB = [&](bf16x8 (&dst)[4][2], int stage) {
    const unsigned short* bp = wBp + stage * stageStride;
#pragma unroll
    for (int n = 0; n < 4; ++n)
#pragma unroll
      for (int ks = 0; ks < 2; ++ks)
        dst[n][ks] = *(const bf16x8*)(bp + n * 1024 + ks * 512);
  };

  bf16x8 bnx[4][2];
  loadB(bnx, 0);                           // stage = tap*4+cc = 0

  for (int cc = 0; cc < 4; ++cc) {
    if (cc) __syncthreads();               // prev slice reads done
#pragma unroll
    for (int j = 0; j < 6; ++j)
      gload16(src + srcOff[j] + cc * 64, smem + j * 4096 + tid * 16);
    __syncthreads();                       // drain staging
#pragma unroll
    for (int tap = 0; tap < 9; ++tap) {
      const int ky = tap / 3, kx = tap - ky * 3;
      bf16x8 bcur[4][2];
#pragma unroll
      for (int n = 0; n < 4; ++n) {
        bcur[n][0] = bnx[n][0];
        bcur[n][1] = bnx[n][1];
      }
      const int nst = (tap < 8) ? ((tap + 1) * 4 + cc) : (cc < 3 ? (cc + 1) : 35);
      loadB(bnx, nst);                     // prefetch next stage (hides L2 lat)
#pragma unroll
      for (int m = 0; m < 4; ++m) {
        const int rA = rBase[m] + ky * 18 + kx;
        const int a0 = rA * 128 + ((k8 ^ (rA & 7)) << 4);
        bf16x8 av0 = *(const bf16x8*)(smem + a0);
        bf16x8 av1 = *(const bf16x8*)(smem + (a0 ^ 64));
#pragma unroll
        for (int n = 0; n < 4; ++n) {
          acc[m][n] = __builtin_amdgcn_mfma_f32_16x16x32_bf16(av0, bcur[n][0], acc[m][n], 0, 0, 0);
          acc[m][n] = __builtin_amdgcn_mfma_f32_16x16x32_bf16(av1, bcur[n][1], acc[m][n], 0, 0, 0);
        }
      }
    }
  }

  // ---- epilogue. C/D frag: col=l15, px_in_frag=k8*4+r (verified layout).
  if constexpr (FINAL) {
    float* cf = (float*)smem;              // [64 px][128 co] fp32 = 32 KB per half
#pragma unroll
    for (int h = 0; h < 2; ++h) {
      __syncthreads();
      if ((wv & 1) == h) {
#pragma unroll
        for (int n = 0; n < 4; ++n) {
          const int col = (wv >> 1) * 64 + n * 16 + l15;
          const int colG = tileN + col;
          const float bvl = (colG < CoutReal) ? bias[colG] : 0.f;
          const int c32 = col >> 2;
#pragma unroll
          for (int m = 0; m < 4; ++m)
#pragma unroll
            for (int r = 0; r < 4; ++r) {
              const int pxl = m * 16 + (k8 << 2) + r;       // 0..63
              const int phys = (c32 + (k8 & 1) * 4) & 31;   // 2-way max
              cf[pxl * 128 + phys * 4 + (col & 3)] = acc[m][n][r] + bvl;
            }
        }
      }
      __syncthreads();
#pragma unroll
      for (int it = 0; it < 8; ++it) {
        const int q = it * 256 + tid;
        const int pxl = q >> 5, c32 = q & 31;
        const int colG = tileN + c32 * 4;
        if (colG < CoutReal) {
          const int phys = (c32 + ((pxl >> 2) & 1) * 4) & 31;
          u32x4 v = *(const u32x4*)(cf + pxl * 128 + phys * 4);
          const int px = h * 64 + pxl;
          const int y = ty + (px >> 4), x = tx + (px & 15);
          const size_t p = ((size_t)(n_img * H + y)) * W + x;
          *(u32x4*)(dstOut + p * CoutReal + colG) = v;
        }
      }
    }
  } else {
    __syncthreads();                       // smem free; reuse as C tile
    unsigned short* cb = (unsigned short*)smem;   // [128 px][128 co] bf16 = 32 KB
#pragma unroll
    for (int n = 0; n < 4; ++n) {
      const int col = (wv >> 1) * 64 + n * 16 + l15;
      const float bvl = bias[tileN + col];
      const int c16 = col >> 3;
#pragma unroll
      for (int m = 0; m < 4; ++m)
#pragma unroll
        for (int r = 0; r < 4; ++r) {
          const int px = (wv & 1) * 64 + m * 16 + (k8 << 2) + r;
          const int phys = (c16 + k8 * 2) & 15;             // conflict-free
          cb[px * 128 + phys * 8 + (col & 7)] = f2bf(fmaxf(acc[m][n][r] + bvl, 0.f));
        }
    }
    __syncthreads();
#pragma unroll
    for (int it = 0; it < 8; ++it) {
      const int q = it * 256 + tid;
      const int px = q >> 4, c16 = q & 15;
      const int phys = (c16 + ((px >> 2) & 3) * 2) & 15;
      u32x4 v = *(const u32x4*)(cb + px * 128 + phys * 8);
      const int y = ty + (px >> 4), x = tx + (px & 15);
      const size_t o = ((size_t)(n_img * Hp + y + 1) * RL + x + 1) * 256 + tileN + c16 * 8;
      *(u32x4*)(dstAct + o) = v;
    }
  }
}

// ---------------------------------------------------------------- host
static void run_branch(const unsigned short* A, unsigned short* Am, unsigned short* B,
                       const unsigned short* wT, const float* bias,
                       const unsigned short* wTout, const float* biasOut,
                       int CoutReal, int outPhases, int NBf, float* out,
                       int H, int lntx, int lnty, hipStream_t stream) {
  dim3 blk(256);
  const int np = 8 * (H / 16) * (H / 8);
  dim3 g1(np, 2);
  conv3x3_k<false><<<g1, blk, 0, stream>>>(A,  wT + 0L * 589824, bias + 0,   B,  nullptr, H, lntx, lnty, 256, 16);
  conv3x3_k<false><<<g1, blk, 0, stream>>>(B,  wT + 1L * 589824, bias + 256, Am, nullptr, H, lntx, lnty, 256, 16);
  conv3x3_k<false><<<g1, blk, 0, stream>>>(Am, wT + 2L * 589824, bias + 512, B,  nullptr, H, lntx, lnty, 256, 16);
  conv3x3_k<false><<<g1, blk, 0, stream>>>(B,  wT + 3L * 589824, bias + 768, Am, nullptr, H, lntx, lnty, 256, 16);
  dim3 g2(np, outPhases);
  conv3x3_k<true><<<g2, blk, 0, stream>>>(Am, wTout, biasOut, nullptr, out, H, lntx, lnty, CoutReal, NBf);
}

extern "C" void kernel_launch(void* const* d_in, const int* in_sizes, int n_in,
                              void* d_out, int out_size, void* d_ws, size_t ws_size,
                              hipStream_t stream) {
  const float* x[3] = {(const float*)d_in[0], (const float*)d_in[1], (const float*)d_in[2]};
  const float* cls_w      = (const float*)d_in[3];
  const float* cls_b      = (const float*)d_in[4];
  const float* bbox_w     = (const float*)d_in[5];
  const float* bbox_b     = (const float*)d_in[6];
  const float* cls_out_w  = (const float*)d_in[7];
  const float* cls_out_b  = (const float*)d_in[8];
  const float* bbox_out_w = (const float*)d_in[9];
  const float* bbox_out_b = (const float*)d_in[10];
  float* out = (float*)d_out;

  char* ws = (char*)d_ws;
  unsigned short* bufA = (unsigned short*)ws;
  unsigned short* bufB = (unsigned short*)(ws + 69222400);
  unsigned short* wt   = (unsigned short*)(ws + 138444800);
  unsigned short* wT_cls      = wt;
  unsigned short* wT_bbox     = wt + 4L * 589824;
  unsigned short* wT_cls_out  = wt + 8L * 589824;         // 36*48*2*512 = 1769472
  unsigned short* wT_bbox_out = wT_cls_out + 2211840;     // 36*8*2*512 = 294912

  for (int i = 0; i < 4; ++i) {
    conv_w_k<<<288, 256, 0, stream>>>(cls_w  + (long)i * 589824, wT_cls  + (long)i * 589824, 256, 16, 73728);
    conv_w_k<<<288, 256, 0, stream>>>(bbox_w + (long)i * 589824, wT_bbox + (long)i * 589824, 256, 16, 73728);
  }
  conv_w_k<<<864, 256, 0, stream>>>(cls_out_w,  wT_cls_out,  720, 48, 221184);
  conv_w_k<<<144, 256, 0, stream>>>(bbox_out_w, wT_bbox_out, 36, 8, 36864);

  const long clsOff[3] = {0L, 94371840L, 117964800L};
  const long boxOff[3] = {123863040L, 128581632L, 129761280L};
  const int Hs[3]    = {128, 64, 32};
  const int lntxs[3] = {3, 2, 1};
  const int lntys[3] = {4, 3, 2};

  for (int lv = 0; lv < 3; ++lv) {
    const int H = Hs[lv], Hp = H + 2;
    const int paddedElems = 8 * Hp * Hp * 256;
    const int totalConv = 8 * Hp * Hp * 32;

    zero_k<<<2048, 256, 0, stream>>>((u32x4*)bufB, paddedElems / 8);

    conv_in_k<<<(totalConv + 255) / 256, 256, 0, stream>>>(x[lv], bufA, H, totalConv);
    run_branch(bufA, bufA, bufB, wT_cls, cls_b, wT_cls_out, cls_out_b,
               720, 6, 48, out + clsOff[lv], H, lntxs[lv], lntys[lv], stream);

    conv_in_k<<<(totalConv + 255) / 256, 256, 0, stream>>>(x[lv], bufA, H, totalConv);
    run_branch(bufA, bufA, bufB, wT_bbox, bbox_b, wT_bbox_out, bbox_out_b,
               36, 1, 8, out + boxOff[lv], H, lntxs[lv], lntys[lv], stream);
  }
}

// Round 6
// 2470.647 us; speedup vs baseline: 4.0906x; 1.0461x over previous
//
#include <hip/hip_runtime.h>
#include <stdint.h>

typedef __attribute__((ext_vector_type(8))) short bf16x8;
typedef __attribute__((ext_vector_type(4))) float f32x4;
typedef __attribute__((ext_vector_type(4))) unsigned int u32x4;

__device__ __forceinline__ unsigned short f2bf(float f) {
  unsigned int u = __float_as_uint(f);
  return (unsigned short)((u + 0x7fffu + ((u >> 16) & 1u)) >> 16);  // RNE
}

__device__ __forceinline__ void gload16(const void* g, void* l) {
  __builtin_amdgcn_global_load_lds((const __attribute__((address_space(1))) void*)g,
                                   (__attribute__((address_space(3))) void*)l, 16, 0, 0);
}

// ---------------------------------------------------------------- zero
__global__ void zero_k(u32x4* __restrict__ p, int n16) {
  int i = blockIdx.x * blockDim.x + threadIdx.x;
  int stride = gridDim.x * blockDim.x;
  u32x4 z = {0u, 0u, 0u, 0u};
  for (; i < n16; i += stride) p[i] = z;
}

// ------------------------------------------- fp32 NHWC -> padded bf16 NHWC
__global__ void conv_in_k(const float* __restrict__ x, unsigned short* __restrict__ dst,
                          int H, int total) {
  int idx = blockIdx.x * 256 + threadIdx.x;
  if (idx >= total) return;
  const int W = H, Hp = H + 2, Wp = H + 2;
  int c8 = idx & 31;
  int rest = idx >> 5;
  int xp = rest % Wp;
  int r2 = rest / Wp;
  int yp = r2 % Hp;
  int n = r2 / Hp;
  u32x4 o = {0u, 0u, 0u, 0u};
  int iy = yp - 1, ix = xp - 1;
  if ((unsigned)iy < (unsigned)H && (unsigned)ix < (unsigned)W) {
    const float* s = x + ((long)((n * H + iy) * W + ix) * 256 + c8 * 8);
    float4 a = *(const float4*)s;
    float4 b = *(const float4*)(s + 4);
    o.x = f2bf(a.x) | ((unsigned)f2bf(a.y) << 16);
    o.y = f2bf(a.z) | ((unsigned)f2bf(a.w) << 16);
    o.z = f2bf(b.x) | ((unsigned)f2bf(b.y) << 16);
    o.w = f2bf(b.z) | ((unsigned)f2bf(b.w) << 16);
  }
  *(u32x4*)(dst + (long)idx * 8) = o;
}

// -------- HWIO fp32 -> bf16 MFMA-fragment layout (verified R2-R5)
// chunk f: l=f&63; ks=(f>>6)&1; jg=(f>>7)%NB; stage=(f>>7)/NB  (stage = tap*4+cc)
__global__ void conv_w_k(const float* __restrict__ w, unsigned short* __restrict__ wTf,
                         int CoutReal, int NB, int totalChunks) {
  int f = blockIdx.x * 256 + threadIdx.x;
  if (f >= totalChunks) return;
  int l = f & 63;
  int t2 = f >> 6;
  int ks = t2 & 1;
  int t3 = t2 >> 1;
  int jg = t3 % NB;
  int stage = t3 / NB;
  int col = jg * 16 + (l & 15);
  int kbase = stage * 64 + ks * 32 + ((l >> 4) << 3);
  u32x4 o = {0u, 0u, 0u, 0u};
  if (col < CoutReal) {
    unsigned short v[8];
#pragma unroll
    for (int e = 0; e < 8; ++e)
      v[e] = f2bf(w[(long)(kbase + e) * CoutReal + col]);
    o.x = v[0] | ((unsigned)v[1] << 16);
    o.y = v[2] | ((unsigned)v[3] << 16);
    o.z = v[4] | ((unsigned)v[5] << 16);
    o.w = v[6] | ((unsigned)v[7] << 16);
  }
  *(u32x4*)(wTf + (long)f * 8) = o;
}

// ---------------------------------------------------------------- conv 3x3
// Tile = 8x16 pixel patch (128 px) x 128 couts. 4 waves: wave = 64 px x 64 co,
// acc[4][4]=64 VGPR. A: DOUBLE-BUFFERED LDS halo [10 y][18 x][64 ch] per
// cc-slice; phase cc issues stage for cc+1 into buf^1 BEFORE computing taps
// (T14 issue-early/drain-late: load latency hides under 288 MFMAs). B:
// register fragments from L2, next-tap prefetch (bcur/bnx).
template<bool FINAL>
__global__ __launch_bounds__(256, 2)
void conv3x3_k(const unsigned short* __restrict__ src,
               const unsigned short* __restrict__ wTf,
               const float* __restrict__ bias,
               unsigned short* __restrict__ dstAct,
               float* __restrict__ dstOut,
               int H, int lntx, int lnty, int CoutReal, int NB)
{
  __shared__ char smem[49152];   // A dbuf: [0,24576)+[24576,49152); epilogue reuses [0,32768)
  const int tid = threadIdx.x;
  const int W = H, Hp = H + 2, RL = H + 2;
  const int np = gridDim.x;
  const int bx = blockIdx.x;
  const int t = (bx & 7) * (np >> 3) + (bx >> 3);      // XCD-chunked swizzle
  const int tx = (t & ((1 << lntx) - 1)) << 4;
  const int ty = ((t >> lntx) & ((1 << lnty) - 1)) << 3;
  const int n_img = t >> (lntx + lnty);
  const int tileN = blockIdx.y * 128;

  // A staging: 180 halo rows (10y x 18x) x 128 B = 1440 chunks; 6 x 256 thr
  int srcOff[6];
#pragma unroll
  for (int j = 0; j < 6; ++j) {
    int q = j * 256 + tid;
    int hr = q >> 3, c = q & 7;
    if (hr >= 180) hr = 0;                 // tail dup, written past read region
    int hy = hr / 18, hx = hr - hy * 18;
    int lch = c ^ (hr & 7);                // inverse swizzle on global source
    srcOff[j] = ((n_img * Hp + ty + hy) * RL + tx + hx) * 256 + lch * 8;
  }

  const int lane = tid & 63;
  const int wv = tid >> 6;
  const int l15 = lane & 15;
  const int k8 = lane >> 4;
  const int pxRow = (wv & 1) * 4;          // wave's first pixel row (of 8)
  const int jgBase = (tileN >> 4) + (wv >> 1) * 4;
  const unsigned short* wBp = wTf + (size_t)jgBase * 1024 + lane * 8;
  const size_t stageStride = (size_t)NB << 10;

  int rBase[4];
#pragma unroll
  for (int m = 0; m < 4; ++m)
    rBase[m] = (pxRow + m) * 18 + l15;

  f32x4 acc[4][4];
#pragma unroll
  for (int m = 0; m < 4; ++m)
#pragma unroll
    for (int n = 0; n < 4; ++n)
      acc[m][n] = (f32x4){0.f, 0.f, 0.f, 0.f};

  auto loadB = [&](bf16x8 (&dst)[4][2], int stage) {
    const unsigned short* bp = wBp + stage * stageStride;
#pragma unroll
    for (int n = 0; n < 4; ++n)
#pragma unroll
      for (int ks = 0; ks < 2; ++ks)
        dst[n][ks] = *(const bf16x8*)(bp + n * 1024 + ks * 512);
  };

  bf16x8 bnx[4][2];
  loadB(bnx, 0);                           // stage = tap*4+cc = 0

  // prologue: stage cc=0 into buf0
#pragma unroll
  for (int j = 0; j < 6; ++j)
    gload16(src + srcOff[j], smem + j * 4096 + tid * 16);
  __syncthreads();

  for (int cc = 0; cc < 4; ++cc) {
    char* cbuf = smem + (cc & 1) * 24576;
    if (cc < 3) {                          // issue next slice early (T14)
      char* nbuf = smem + ((cc + 1) & 1) * 24576;
#pragma unroll
      for (int j = 0; j < 6; ++j)
        gload16(src + srcOff[j] + (cc + 1) * 64, nbuf + j * 4096 + tid * 16);
    }
#pragma unroll
    for (int tap = 0; tap < 9; ++tap) {
      const int ky = tap / 3, kx = tap - ky * 3;
      bf16x8 bcur[4][2];
#pragma unroll
      for (int n = 0; n < 4; ++n) {
        bcur[n][0] = bnx[n][0];
        bcur[n][1] = bnx[n][1];
      }
      const int nst = (tap < 8) ? ((tap + 1) * 4 + cc) : (cc < 3 ? (cc + 1) : 35);
      loadB(bnx, nst);                     // prefetch next stage (hides L2 lat)
#pragma unroll
      for (int m = 0; m < 4; ++m) {
        const int rA = rBase[m] + ky * 18 + kx;
        const int a0 = rA * 128 + ((k8 ^ (rA & 7)) << 4);
        bf16x8 av0 = *(const bf16x8*)(cbuf + a0);
        bf16x8 av1 = *(const bf16x8*)(cbuf + (a0 ^ 64));
#pragma unroll
        for (int n = 0; n < 4; ++n) {
          acc[m][n] = __builtin_amdgcn_mfma_f32_16x16x32_bf16(av0, bcur[n][0], acc[m][n], 0, 0, 0);
          acc[m][n] = __builtin_amdgcn_mfma_f32_16x16x32_bf16(av1, bcur[n][1], acc[m][n], 0, 0, 0);
        }
      }
    }
    __syncthreads();                       // drains vmcnt: next buf ready; reads done
  }

  // ---- epilogue. C/D frag: col=l15, px_in_frag=k8*4+r (verified layout).
  if constexpr (FINAL) {
    float* cf = (float*)smem;              // [64 px][128 co] fp32 = 32 KB per half
#pragma unroll
    for (int h = 0; h < 2; ++h) {
      if (h) __syncthreads();
      if ((wv & 1) == h) {
#pragma unroll
        for (int n = 0; n < 4; ++n) {
          const int col = (wv >> 1) * 64 + n * 16 + l15;
          const int colG = tileN + col;
          const float bvl = (colG < CoutReal) ? bias[colG] : 0.f;
          const int c32 = col >> 2;
#pragma unroll
          for (int m = 0; m < 4; ++m)
#pragma unroll
            for (int r = 0; r < 4; ++r) {
              const int pxl = m * 16 + (k8 << 2) + r;       // 0..63
              const int phys = (c32 + (k8 & 1) * 4) & 31;   // 2-way max
              cf[pxl * 128 + phys * 4 + (col & 3)] = acc[m][n][r] + bvl;
            }
        }
      }
      __syncthreads();
#pragma unroll
      for (int it = 0; it < 8; ++it) {
        const int q = it * 256 + tid;
        const int pxl = q >> 5, c32 = q & 31;
        const int colG = tileN + c32 * 4;
        if (colG < CoutReal) {
          const int phys = (c32 + ((pxl >> 2) & 1) * 4) & 31;
          u32x4 v = *(const u32x4*)(cf + pxl * 128 + phys * 4);
          const int px = h * 64 + pxl;
          const int y = ty + (px >> 4), x = tx + (px & 15);
          const size_t p = ((size_t)(n_img * H + y)) * W + x;
          *(u32x4*)(dstOut + p * CoutReal + colG) = v;
        }
      }
    }
  } else {
    unsigned short* cb = (unsigned short*)smem;   // [128 px][128 co] bf16 = 32 KB
#pragma unroll
    for (int n = 0; n < 4; ++n) {
      const int col = (wv >> 1) * 64 + n * 16 + l15;
      const float bvl = bias[tileN + col];
      const int c16 = col >> 3;
#pragma unroll
      for (int m = 0; m < 4; ++m)
#pragma unroll
        for (int r = 0; r < 4; ++r) {
          const int px = (wv & 1) * 64 + m * 16 + (k8 << 2) + r;
          const int phys = (c16 + k8 * 2) & 15;             // conflict-free
          cb[px * 128 + phys * 8 + (col & 7)] = f2bf(fmaxf(acc[m][n][r] + bvl, 0.f));
        }
    }
    __syncthreads();
#pragma unroll
    for (int it = 0; it < 8; ++it) {
      const int q = it * 256 + tid;
      const int px = q >> 4, c16 = q & 15;
      const int phys = (c16 + ((px >> 2) & 3) * 2) & 15;
      u32x4 v = *(const u32x4*)(cb + px * 128 + phys * 8);
      const int y = ty + (px >> 4), x = tx + (px & 15);
      const size_t o = ((size_t)(n_img * Hp + y + 1) * RL + x + 1) * 256 + tileN + c16 * 8;
      *(u32x4*)(dstAct + o) = v;
    }
  }
}

// ---------------------------------------------------------------- host
static void run_branch(const unsigned short* A, unsigned short* Am, unsigned short* B,
                       const unsigned short* wT, const float* bias,
                       const unsigned short* wTout, const float* biasOut,
                       int CoutReal, int outPhases, int NBf, float* out,
                       int H, int lntx, int lnty, hipStream_t stream) {
  dim3 blk(256);
  const int np = 8 * (H / 16) * (H / 8);
  dim3 g1(np, 2);
  conv3x3_k<false><<<g1, blk, 0, stream>>>(A,  wT + 0L * 589824, bias + 0,   B,  nullptr, H, lntx, lnty, 256, 16);
  conv3x3_k<false><<<g1, blk, 0, stream>>>(B,  wT + 1L * 589824, bias + 256, Am, nullptr, H, lntx, lnty, 256, 16);
  conv3x3_k<false><<<g1, blk, 0, stream>>>(Am, wT + 2L * 589824, bias + 512, B,  nullptr, H, lntx, lnty, 256, 16);
  conv3x3_k<false><<<g1, blk, 0, stream>>>(B,  wT + 3L * 589824, bias + 768, Am, nullptr, H, lntx, lnty, 256, 16);
  dim3 g2(np, outPhases);
  conv3x3_k<true><<<g2, blk, 0, stream>>>(Am, wTout, biasOut, nullptr, out, H, lntx, lnty, CoutReal, NBf);
}

extern "C" void kernel_launch(void* const* d_in, const int* in_sizes, int n_in,
                              void* d_out, int out_size, void* d_ws, size_t ws_size,
                              hipStream_t stream) {
  const float* x[3] = {(const float*)d_in[0], (const float*)d_in[1], (const float*)d_in[2]};
  const float* cls_w      = (const float*)d_in[3];
  const float* cls_b      = (const float*)d_in[4];
  const float* bbox_w     = (const float*)d_in[5];
  const float* bbox_b     = (const float*)d_in[6];
  const float* cls_out_w  = (const float*)d_in[7];
  const float* cls_out_b  = (const float*)d_in[8];
  const float* bbox_out_w = (const float*)d_in[9];
  const float* bbox_out_b = (const float*)d_in[10];
  float* out = (float*)d_out;

  char* ws = (char*)d_ws;
  unsigned short* bufA = (unsigned short*)ws;
  unsigned short* bufB = (unsigned short*)(ws + 69222400);
  unsigned short* wt   = (unsigned short*)(ws + 138444800);
  unsigned short* wT_cls      = wt;
  unsigned short* wT_bbox     = wt + 4L * 589824;
  unsigned short* wT_cls_out  = wt + 8L * 589824;         // 36*48*2*512 = 1769472
  unsigned short* wT_bbox_out = wT_cls_out + 2211840;     // 36*8*2*512 = 294912

  for (int i = 0; i < 4; ++i) {
    conv_w_k<<<288, 256, 0, stream>>>(cls_w  + (long)i * 589824, wT_cls  + (long)i * 589824, 256, 16, 73728);
    conv_w_k<<<288, 256, 0, stream>>>(bbox_w + (long)i * 589824, wT_bbox + (long)i * 589824, 256, 16, 73728);
  }
  conv_w_k<<<864, 256, 0, stream>>>(cls_out_w,  wT_cls_out,  720, 48, 221184);
  conv_w_k<<<144, 256, 0, stream>>>(bbox_out_w, wT_bbox_out, 36, 8, 36864);

  const long clsOff[3] = {0L, 94371840L, 117964800L};
  const long boxOff[3] = {123863040L, 128581632L, 129761280L};
  const int Hs[3]    = {128, 64, 32};
  const int lntxs[3] = {3, 2, 1};
  const int lntys[3] = {4, 3, 2};

  for (int lv = 0; lv < 3; ++lv) {
    const int H = Hs[lv], Hp = H + 2;
    const int paddedElems = 8 * Hp * Hp * 256;
    const int totalConv = 8 * Hp * Hp * 32;

    zero_k<<<2048, 256, 0, stream>>>((u32x4*)bufB, paddedElems / 8);

    conv_in_k<<<(totalConv + 255) / 256, 256, 0, stream>>>(x[lv], bufA, H, totalConv);
    run_branch(bufA, bufA, bufB, wT_cls, cls_b, wT_cls_out, cls_out_b,
               720, 6, 48, out + clsOff[lv], H, lntxs[lv], lntys[lv], stream);

    conv_in_k<<<(totalConv + 255) / 256, 256, 0, stream>>>(x[lv], bufA, H, totalConv);
    run_branch(bufA, bufA, bufB, wT_bbox, bbox_b, wT_bbox_out, bbox_out_b,
               36, 1, 8, out + boxOff[lv], H, lntxs[lv], lntys[lv], stream);
  }
}

// Round 7
// 2177.320 us; speedup vs baseline: 4.6416x; 1.1347x over previous
//
#include <hip/hip_runtime.h>
#include <stdint.h>

typedef __attribute__((ext_vector_type(8))) short bf16x8;
typedef __attribute__((ext_vector_type(4))) float f32x4;
typedef __attribute__((ext_vector_type(4))) unsigned int u32x4;

__device__ __forceinline__ unsigned short f2bf(float f) {
  unsigned int u = __float_as_uint(f);
  return (unsigned short)((u + 0x7fffu + ((u >> 16) & 1u)) >> 16);  // RNE
}

__device__ __forceinline__ void gload16(const void* g, void* l) {
  __builtin_amdgcn_global_load_lds((const __attribute__((address_space(1))) void*)g,
                                   (__attribute__((address_space(3))) void*)l, 16, 0, 0);
}

// ---------------------------------------------------------------- zero
__global__ void zero_k(u32x4* __restrict__ p, int n16) {
  int i = blockIdx.x * blockDim.x + threadIdx.x;
  int stride = gridDim.x * blockDim.x;
  u32x4 z = {0u, 0u, 0u, 0u};
  for (; i < n16; i += stride) p[i] = z;
}

// ------------------------------------------- fp32 NHWC -> padded bf16 NHWC
__global__ void conv_in_k(const float* __restrict__ x, unsigned short* __restrict__ dst,
                          int H, int total) {
  int idx = blockIdx.x * 256 + threadIdx.x;
  if (idx >= total) return;
  const int W = H, Hp = H + 2, Wp = H + 2;
  int c8 = idx & 31;
  int rest = idx >> 5;
  int xp = rest % Wp;
  int r2 = rest / Wp;
  int yp = r2 % Hp;
  int n = r2 / Hp;
  u32x4 o = {0u, 0u, 0u, 0u};
  int iy = yp - 1, ix = xp - 1;
  if ((unsigned)iy < (unsigned)H && (unsigned)ix < (unsigned)W) {
    const float* s = x + ((long)((n * H + iy) * W + ix) * 256 + c8 * 8);
    float4 a = *(const float4*)s;
    float4 b = *(const float4*)(s + 4);
    o.x = f2bf(a.x) | ((unsigned)f2bf(a.y) << 16);
    o.y = f2bf(a.z) | ((unsigned)f2bf(a.w) << 16);
    o.z = f2bf(b.x) | ((unsigned)f2bf(b.y) << 16);
    o.w = f2bf(b.z) | ((unsigned)f2bf(b.w) << 16);
  }
  *(u32x4*)(dst + (long)idx * 8) = o;
}

// -------- HWIO fp32 -> bf16 MFMA-fragment layout (verified R2-R6)
// chunk f: l=f&63; ks=(f>>6)&1; jg=(f>>7)%NB; stage=(f>>7)/NB  (stage = tap*4+cc)
__global__ void conv_w_k(const float* __restrict__ w, unsigned short* __restrict__ wTf,
                         int CoutReal, int NB, int totalChunks) {
  int f = blockIdx.x * 256 + threadIdx.x;
  if (f >= totalChunks) return;
  int l = f & 63;
  int t2 = f >> 6;
  int ks = t2 & 1;
  int t3 = t2 >> 1;
  int jg = t3 % NB;
  int stage = t3 / NB;
  int col = jg * 16 + (l & 15);
  int kbase = stage * 64 + ks * 32 + ((l >> 4) << 3);
  u32x4 o = {0u, 0u, 0u, 0u};
  if (col < CoutReal) {
    unsigned short v[8];
#pragma unroll
    for (int e = 0; e < 8; ++e)
      v[e] = f2bf(w[(long)(kbase + e) * CoutReal + col]);
    o.x = v[0] | ((unsigned)v[1] << 16);
    o.y = v[2] | ((unsigned)v[3] << 16);
    o.z = v[4] | ((unsigned)v[5] << 16);
    o.w = v[6] | ((unsigned)v[7] << 16);
  }
  *(u32x4*)(wTf + (long)f * 8) = o;
}

// ---------------------------------------------------------------- conv 3x3
// Tile = 8x16 px patch (128 px) x NF*32 couts. 4 waves: wave = 64 px x NF*16 co.
// A: double-buffered LDS halo [10][18][64ch] per cc (T14 issue-early). B: reg
// fragments from L2, next-tap prefetch. T5: av hoisted per tap, then pure-MFMA
// cluster wrapped in s_setprio(1)/(0).
template<int NF, bool FINAL>
__global__ __launch_bounds__(256, 2)
void conv3x3_k(const unsigned short* __restrict__ src,
               const unsigned short* __restrict__ wTf,
               const float* __restrict__ bias,
               unsigned short* __restrict__ dstAct,
               float* __restrict__ dstOut,
               int H, int lntx, int lnty, int CoutReal, int NB)
{
  __shared__ char smem[49152];   // A dbuf: [0,24576)+[24576,49152); epilogue reuses [0,32768)
  const int tid = threadIdx.x;
  const int W = H, Hp = H + 2, RL = H + 2;
  const int np = gridDim.x;
  const int bx = blockIdx.x;
  const int t = (bx & 7) * (np >> 3) + (bx >> 3);      // XCD-chunked swizzle
  const int tx = (t & ((1 << lntx) - 1)) << 4;
  const int ty = ((t >> lntx) & ((1 << lnty) - 1)) << 3;
  const int n_img = t >> (lntx + lnty);
  const int tileN = blockIdx.y * (NF * 32);

  // A staging: 180 halo rows (10y x 18x) x 128 B = 1440 chunks; 6 x 256 thr
  int srcOff[6];
#pragma unroll
  for (int j = 0; j < 6; ++j) {
    int q = j * 256 + tid;
    int hr = q >> 3, c = q & 7;
    if (hr >= 180) hr = 0;                 // tail dup, harmless
    int hy = hr / 18, hx = hr - hy * 18;
    int lch = c ^ (hr & 7);                // inverse swizzle on global source
    srcOff[j] = ((n_img * Hp + ty + hy) * RL + tx + hx) * 256 + lch * 8;
  }

  const int lane = tid & 63;
  const int wv = tid >> 6;
  const int l15 = lane & 15;
  const int k8 = lane >> 4;
  const int pxRow = (wv & 1) * 4;          // wave's first pixel row (of 8)
  const int jgBase = (tileN >> 4) + (wv >> 1) * NF;
  const unsigned short* wBp = wTf + (size_t)jgBase * 1024 + lane * 8;
  const size_t stageStride = (size_t)NB << 10;

  int rBase[4];
#pragma unroll
  for (int m = 0; m < 4; ++m)
    rBase[m] = (pxRow + m) * 18 + l15;

  f32x4 acc[4][NF];
#pragma unroll
  for (int m = 0; m < 4; ++m)
#pragma unroll
    for (int n = 0; n < NF; ++n)
      acc[m][n] = (f32x4){0.f, 0.f, 0.f, 0.f};

  auto loadB = [&](bf16x8 (&dst)[NF][2], int stage) {
    const unsigned short* bp = wBp + stage * stageStride;
#pragma unroll
    for (int n = 0; n < NF; ++n)
#pragma unroll
      for (int ks = 0; ks < 2; ++ks)
        dst[n][ks] = *(const bf16x8*)(bp + n * 1024 + ks * 512);
  };

  bf16x8 bnx[NF][2];
  loadB(bnx, 0);                           // stage = tap*4+cc = 0

  // prologue: stage cc=0 into buf0
#pragma unroll
  for (int j = 0; j < 6; ++j)
    gload16(src + srcOff[j], smem + j * 4096 + tid * 16);
  __syncthreads();

  for (int cc = 0; cc < 4; ++cc) {
    char* cbuf = smem + (cc & 1) * 24576;
    if (cc < 3) {                          // issue next slice early (T14)
      char* nbuf = smem + ((cc + 1) & 1) * 24576;
#pragma unroll
      for (int j = 0; j < 6; ++j)
        gload16(src + srcOff[j] + (cc + 1) * 64, nbuf + j * 4096 + tid * 16);
    }
#pragma unroll
    for (int tap = 0; tap < 9; ++tap) {
      const int ky = tap / 3, kx = tap - ky * 3;
      bf16x8 bcur[NF][2];
#pragma unroll
      for (int n = 0; n < NF; ++n) {
        bcur[n][0] = bnx[n][0];
        bcur[n][1] = bnx[n][1];
      }
      // hoist the tap's A fragments (8 ds_read_b128)
      bf16x8 av[4][2];
#pragma unroll
      for (int m = 0; m < 4; ++m) {
        const int rA = rBase[m] + ky * 18 + kx;
        const int a0 = rA * 128 + ((k8 ^ (rA & 7)) << 4);
        av[m][0] = *(const bf16x8*)(cbuf + a0);
        av[m][1] = *(const bf16x8*)(cbuf + (a0 ^ 64));
      }
      const int nst = (tap < 8) ? ((tap + 1) * 4 + cc) : (cc < 3 ? (cc + 1) : 35);
      loadB(bnx, nst);                     // prefetch next stage (hides L2 lat)
      __builtin_amdgcn_s_setprio(1);       // T5: favor MFMA cluster
#pragma unroll
      for (int m = 0; m < 4; ++m)
#pragma unroll
        for (int n = 0; n < NF; ++n) {
          acc[m][n] = __builtin_amdgcn_mfma_f32_16x16x32_bf16(av[m][0], bcur[n][0], acc[m][n], 0, 0, 0);
          acc[m][n] = __builtin_amdgcn_mfma_f32_16x16x32_bf16(av[m][1], bcur[n][1], acc[m][n], 0, 0, 0);
        }
      __builtin_amdgcn_s_setprio(0);
    }
    __syncthreads();                       // drains vmcnt: next buf ready; reads done
  }

  // ---- epilogue. C/D frag: col=l15, px_in_frag=k8*4+r (verified layout).
  if constexpr (FINAL) {
    constexpr int NCOL = NF * 32;
    constexpr int MASK = NCOL / 4 - 1;
    float* cf = (float*)smem;              // [64 px][NCOL co] fp32 per half
#pragma unroll
    for (int h = 0; h < 2; ++h) {
      if (h) __syncthreads();
      if ((wv & 1) == h) {
#pragma unroll
        for (int n = 0; n < NF; ++n) {
          const int col = (wv >> 1) * (NF * 16) + n * 16 + l15;
          const int colG = tileN + col;
          const float bvl = (colG < CoutReal) ? bias[colG] : 0.f;
          const int c32 = col >> 2;
#pragma unroll
          for (int m = 0; m < 4; ++m)
#pragma unroll
            for (int r = 0; r < 4; ++r) {
              const int pxl = m * 16 + (k8 << 2) + r;       // 0..63
              const int phys = (c32 + (k8 & 1) * 4) & MASK; // 2-way max
              cf[pxl * NCOL + phys * 4 + (col & 3)] = acc[m][n][r] + bvl;
            }
        }
      }
      __syncthreads();
#pragma unroll
      for (int it = 0; it < NCOL / 16; ++it) {
        const int q = it * 256 + tid;
        const int pxl = q / (NCOL / 4), c32 = q & MASK;
        const int colG = tileN + c32 * 4;
        if (colG < CoutReal) {
          const int phys = (c32 + ((pxl >> 2) & 1) * 4) & MASK;
          u32x4 v = *(const u32x4*)(cf + pxl * NCOL + phys * 4);
          const int px = h * 64 + pxl;
          const int y = ty + (px >> 4), x = tx + (px & 15);
          const size_t p = ((size_t)(n_img * H + y)) * W + x;
          *(u32x4*)(dstOut + p * CoutReal + colG) = v;
        }
      }
    }
  } else {
    unsigned short* cb = (unsigned short*)smem;   // [128 px][128 co] bf16 = 32 KB
#pragma unroll
    for (int n = 0; n < NF; ++n) {
      const int col = (wv >> 1) * (NF * 16) + n * 16 + l15;
      const float bvl = bias[tileN + col];
      const int c16 = col >> 3;
#pragma unroll
      for (int m = 0; m < 4; ++m)
#pragma unroll
        for (int r = 0; r < 4; ++r) {
          const int px = (wv & 1) * 64 + m * 16 + (k8 << 2) + r;
          const int phys = (c16 + k8 * 2) & 15;             // conflict-free
          cb[px * 128 + phys * 8 + (col & 7)] = f2bf(fmaxf(acc[m][n][r] + bvl, 0.f));
        }
    }
    __syncthreads();
#pragma unroll
    for (int it = 0; it < 8; ++it) {
      const int q = it * 256 + tid;
      const int px = q >> 4, c16 = q & 15;
      const int phys = (c16 + ((px >> 2) & 3) * 2) & 15;
      u32x4 v = *(const u32x4*)(cb + px * 128 + phys * 8);
      const int y = ty + (px >> 4), x = tx + (px & 15);
      const size_t o = ((size_t)(n_img * Hp + y + 1) * RL + x + 1) * 256 + tileN + c16 * 8;
      *(u32x4*)(dstAct + o) = v;
    }
  }
}

// ---------------------------------------------------------------- host
static void run_branch(const unsigned short* A, unsigned short* Am, unsigned short* B,
                       const unsigned short* wT, const float* bias,
                       const unsigned short* wTout, const float* biasOut,
                       bool cls, float* out, int H, int lntx, int lnty,
                       hipStream_t stream) {
  dim3 blk(256);
  const int np = 8 * (H / 16) * (H / 8);
  dim3 g1(np, 2);
  conv3x3_k<4, false><<<g1, blk, 0, stream>>>(A,  wT + 0L * 589824, bias + 0,   B,  nullptr, H, lntx, lnty, 256, 16);
  conv3x3_k<4, false><<<g1, blk, 0, stream>>>(B,  wT + 1L * 589824, bias + 256, Am, nullptr, H, lntx, lnty, 256, 16);
  conv3x3_k<4, false><<<g1, blk, 0, stream>>>(Am, wT + 2L * 589824, bias + 512, B,  nullptr, H, lntx, lnty, 256, 16);
  conv3x3_k<4, false><<<g1, blk, 0, stream>>>(B,  wT + 3L * 589824, bias + 768, Am, nullptr, H, lntx, lnty, 256, 16);
  if (cls) {
    dim3 g2(np, 6);
    conv3x3_k<4, true><<<g2, blk, 0, stream>>>(Am, wTout, biasOut, nullptr, out, H, lntx, lnty, 720, 48);
  } else {
    dim3 g2(np, 1);
    conv3x3_k<2, true><<<g2, blk, 0, stream>>>(Am, wTout, biasOut, nullptr, out, H, lntx, lnty, 36, 4);
  }
}

extern "C" void kernel_launch(void* const* d_in, const int* in_sizes, int n_in,
                              void* d_out, int out_size, void* d_ws, size_t ws_size,
                              hipStream_t stream) {
  const float* x[3] = {(const float*)d_in[0], (const float*)d_in[1], (const float*)d_in[2]};
  const float* cls_w      = (const float*)d_in[3];
  const float* cls_b      = (const float*)d_in[4];
  const float* bbox_w     = (const float*)d_in[5];
  const float* bbox_b     = (const float*)d_in[6];
  const float* cls_out_w  = (const float*)d_in[7];
  const float* cls_out_b  = (const float*)d_in[8];
  const float* bbox_out_w = (const float*)d_in[9];
  const float* bbox_out_b = (const float*)d_in[10];
  float* out = (float*)d_out;

  char* ws = (char*)d_ws;
  unsigned short* bufA = (unsigned short*)ws;
  unsigned short* bufB = (unsigned short*)(ws + 69222400);
  unsigned short* wt   = (unsigned short*)(ws + 138444800);
  unsigned short* wT_cls      = wt;
  unsigned short* wT_bbox     = wt + 4L * 589824;
  unsigned short* wT_cls_out  = wt + 8L * 589824;         // 36*48*2*512 = 1769472
  unsigned short* wT_bbox_out = wT_cls_out + 2211840;     // 36*4*2*512 = 147456

  for (int i = 0; i < 4; ++i) {
    conv_w_k<<<288, 256, 0, stream>>>(cls_w  + (long)i * 589824, wT_cls  + (long)i * 589824, 256, 16, 73728);
    conv_w_k<<<288, 256, 0, stream>>>(bbox_w + (long)i * 589824, wT_bbox + (long)i * 589824, 256, 16, 73728);
  }
  conv_w_k<<<864, 256, 0, stream>>>(cls_out_w,  wT_cls_out,  720, 48, 221184);
  conv_w_k<<<72, 256, 0, stream>>>(bbox_out_w, wT_bbox_out, 36, 4, 18432);

  const long clsOff[3] = {0L, 94371840L, 117964800L};
  const long boxOff[3] = {123863040L, 128581632L, 129761280L};
  const int Hs[3]    = {128, 64, 32};
  const int lntxs[3] = {3, 2, 1};
  const int lntys[3] = {4, 3, 2};

  for (int lv = 0; lv < 3; ++lv) {
    const int H = Hs[lv], Hp = H + 2;
    const int paddedElems = 8 * Hp * Hp * 256;
    const int totalConv = 8 * Hp * Hp * 32;

    zero_k<<<2048, 256, 0, stream>>>((u32x4*)bufB, paddedElems / 8);

    conv_in_k<<<(totalConv + 255) / 256, 256, 0, stream>>>(x[lv], bufA, H, totalConv);
    run_branch(bufA, bufA, bufB, wT_cls, cls_b, wT_cls_out, cls_out_b,
               true, out + clsOff[lv], H, lntxs[lv], lntys[lv], stream);

    conv_in_k<<<(totalConv + 255) / 256, 256, 0, stream>>>(x[lv], bufA, H, totalConv);
    run_branch(bufA, bufA, bufB, wT_bbox, bbox_b, wT_bbox_out, bbox_out_b,
               false, out + boxOff[lv], H, lntxs[lv], lntys[lv], stream);
  }
}

// Round 8
// 2071.643 us; speedup vs baseline: 4.8784x; 1.0510x over previous
//
#include <hip/hip_runtime.h>
#include <stdint.h>

typedef __attribute__((ext_vector_type(8))) short bf16x8;
typedef __attribute__((ext_vector_type(4))) float f32x4;
typedef __attribute__((ext_vector_type(4))) unsigned int u32x4;

__device__ __forceinline__ unsigned short f2bf(float f) {
  unsigned int u = __float_as_uint(f);
  return (unsigned short)((u + 0x7fffu + ((u >> 16) & 1u)) >> 16);  // RNE
}

__device__ __forceinline__ void gload16(const void* g, void* l) {
  __builtin_amdgcn_global_load_lds((const __attribute__((address_space(1))) void*)g,
                                   (__attribute__((address_space(3))) void*)l, 16, 0, 0);
}

// ---------------------------------------------------------------- zero
__global__ void zero_k(u32x4* __restrict__ p, int n16) {
  int i = blockIdx.x * blockDim.x + threadIdx.x;
  int stride = gridDim.x * blockDim.x;
  u32x4 z = {0u, 0u, 0u, 0u};
  for (; i < n16; i += stride) p[i] = z;
}

// ------------------------------------------- fp32 NHWC -> padded bf16 NHWC
__global__ void conv_in_k(const float* __restrict__ x, unsigned short* __restrict__ dst,
                          int H, int total) {
  int idx = blockIdx.x * 256 + threadIdx.x;
  if (idx >= total) return;
  const int W = H, Hp = H + 2, Wp = H + 2;
  int c8 = idx & 31;
  int rest = idx >> 5;
  int xp = rest % Wp;
  int r2 = rest / Wp;
  int yp = r2 % Hp;
  int n = r2 / Hp;
  u32x4 o = {0u, 0u, 0u, 0u};
  int iy = yp - 1, ix = xp - 1;
  if ((unsigned)iy < (unsigned)H && (unsigned)ix < (unsigned)W) {
    const float* s = x + ((long)((n * H + iy) * W + ix) * 256 + c8 * 8);
    float4 a = *(const float4*)s;
    float4 b = *(const float4*)(s + 4);
    o.x = f2bf(a.x) | ((unsigned)f2bf(a.y) << 16);
    o.y = f2bf(a.z) | ((unsigned)f2bf(a.w) << 16);
    o.z = f2bf(b.x) | ((unsigned)f2bf(b.y) << 16);
    o.w = f2bf(b.z) | ((unsigned)f2bf(b.w) << 16);
  }
  *(u32x4*)(dst + (long)idx * 8) = o;
}

// -------- HWIO fp32 -> bf16 MFMA-fragment layout (verified R2-R7)
// chunk f: l=f&63; ks=(f>>6)&1; jg=(f>>7)%NB; stage=(f>>7)/NB  (stage = tap*4+cc)
__global__ void conv_w_k(const float* __restrict__ w, unsigned short* __restrict__ wTf,
                         int CoutReal, int NB, int totalChunks) {
  int f = blockIdx.x * 256 + threadIdx.x;
  if (f >= totalChunks) return;
  int l = f & 63;
  int t2 = f >> 6;
  int ks = t2 & 1;
  int t3 = t2 >> 1;
  int jg = t3 % NB;
  int stage = t3 / NB;
  int col = jg * 16 + (l & 15);
  int kbase = stage * 64 + ks * 32 + ((l >> 4) << 3);
  u32x4 o = {0u, 0u, 0u, 0u};
  if (col < CoutReal) {
    unsigned short v[8];
#pragma unroll
    for (int e = 0; e < 8; ++e)
      v[e] = f2bf(w[(long)(kbase + e) * CoutReal + col]);
    o.x = v[0] | ((unsigned)v[1] << 16);
    o.y = v[2] | ((unsigned)v[3] << 16);
    o.z = v[4] | ((unsigned)v[5] << 16);
    o.w = v[6] | ((unsigned)v[7] << 16);
  }
  *(u32x4*)(wTf + (long)f * 8) = o;
}

// ---------------------------------------------------------------- conv 3x3
// Tile = 8x16 px patch (128 px) x NF*32 couts. 4 waves: wave = 64 px x NF*16 co.
// A: double-buffered LDS halo [10][18][64ch] per cc (T14 issue-early).
// BOTH operand streams ring-2 software-pipelined: during tap t's pure-MFMA
// cluster (T5 setprio-wrapped), av ds_reads and B global loads for tap t+1
// are issued. cc loop fully unrolled so ring parity s=cc*9+tap is static
// (rule #20). No av prefetch across the cc barrier (staging race).
template<int NF, bool FINAL>
__global__ __launch_bounds__(256, 2)
void conv3x3_k(const unsigned short* __restrict__ src,
               const unsigned short* __restrict__ wTf,
               const float* __restrict__ bias,
               unsigned short* __restrict__ dstAct,
               float* __restrict__ dstOut,
               int H, int lntx, int lnty, int CoutReal, int NB)
{
  __shared__ char smem[49152];   // A dbuf: [0,24576)+[24576,49152); epilogue reuses [0,32768)
  const int tid = threadIdx.x;
  const int W = H, Hp = H + 2, RL = H + 2;
  const int np = gridDim.x;
  const int bx = blockIdx.x;
  const int t = (bx & 7) * (np >> 3) + (bx >> 3);      // XCD-chunked swizzle
  const int tx = (t & ((1 << lntx) - 1)) << 4;
  const int ty = ((t >> lntx) & ((1 << lnty) - 1)) << 3;
  const int n_img = t >> (lntx + lnty);
  const int tileN = blockIdx.y * (NF * 32);

  // A staging: 180 halo rows (10y x 18x) x 128 B = 1440 chunks; 6 x 256 thr
  int srcOff[6];
#pragma unroll
  for (int j = 0; j < 6; ++j) {
    int q = j * 256 + tid;
    int hr = q >> 3, c = q & 7;
    if (hr >= 180) hr = 0;                 // tail dup, harmless
    int hy = hr / 18, hx = hr - hy * 18;
    int lch = c ^ (hr & 7);                // inverse swizzle on global source
    srcOff[j] = ((n_img * Hp + ty + hy) * RL + tx + hx) * 256 + lch * 8;
  }

  const int lane = tid & 63;
  const int wv = tid >> 6;
  const int l15 = lane & 15;
  const int k8 = lane >> 4;
  const int pxRow = (wv & 1) * 4;          // wave's first pixel row (of 8)
  const int jgBase = (tileN >> 4) + (wv >> 1) * NF;
  const unsigned short* wBp = wTf + (size_t)jgBase * 1024 + lane * 8;
  const size_t stageStride = (size_t)NB << 10;

  int rBase[4];
#pragma unroll
  for (int m = 0; m < 4; ++m)
    rBase[m] = (pxRow + m) * 18 + l15;

  f32x4 acc[4][NF];
#pragma unroll
  for (int m = 0; m < 4; ++m)
#pragma unroll
    for (int n = 0; n < NF; ++n)
      acc[m][n] = (f32x4){0.f, 0.f, 0.f, 0.f};

  auto loadB = [&](bf16x8 (&dst)[NF][2], int stage) {
    const unsigned short* bp = wBp + stage * stageStride;
#pragma unroll
    for (int n = 0; n < NF; ++n)
#pragma unroll
      for (int ks = 0; ks < 2; ++ks)
        dst[n][ks] = *(const bf16x8*)(bp + n * 1024 + ks * 512);
  };
  auto loadA = [&](bf16x8 (&dst)[4][2], const char* buf, int tap) {
    const int ky = tap / 3, kx = tap - ky * 3;
#pragma unroll
    for (int m = 0; m < 4; ++m) {
      const int rA = rBase[m] + ky * 18 + kx;
      const int a0 = rA * 128 + ((k8 ^ (rA & 7)) << 4);
      dst[m][0] = *(const bf16x8*)(buf + a0);
      dst[m][1] = *(const bf16x8*)(buf + (a0 ^ 64));
    }
  };

  bf16x8 avr[2][4][2];                     // ring-2 A fragments
  bf16x8 bb[2][NF][2];                     // ring-2 B fragments
  loadB(bb[0], 0);                         // stage (tap0, cc0)

  // prologue: stage cc=0 into buf0
#pragma unroll
  for (int j = 0; j < 6; ++j)
    gload16(src + srcOff[j], smem + j * 4096 + tid * 16);
  __syncthreads();
  loadA(avr[0], smem, 0);                  // av for (cc0, tap0)

#pragma unroll
  for (int cc = 0; cc < 4; ++cc) {
    char* cbuf = smem + (cc & 1) * 24576;
    if (cc < 3) {                          // issue next A slice early (T14)
      char* nbuf = smem + ((cc + 1) & 1) * 24576;
#pragma unroll
      for (int j = 0; j < 6; ++j)
        gload16(src + srcOff[j] + (cc + 1) * 64, nbuf + j * 4096 + tid * 16);
    }
#pragma unroll
    for (int tap = 0; tap < 9; ++tap) {
      const int s = cc * 9 + tap;          // literal: static ring index
      const int cur = s & 1, nxt = cur ^ 1;
      if (tap < 8)
        loadA(avr[nxt], cbuf, tap + 1);    // av for next tap (same LDS buf)
      if (cc < 3 || tap < 8)
        loadB(bb[nxt], (tap < 8) ? ((tap + 1) * 4 + cc) : (cc + 1));
      __builtin_amdgcn_s_setprio(1);       // T5: pure-MFMA cluster
#pragma unroll
      for (int m = 0; m < 4; ++m)
#pragma unroll
        for (int n = 0; n < NF; ++n) {
          acc[m][n] = __builtin_amdgcn_mfma_f32_16x16x32_bf16(avr[cur][m][0], bb[cur][n][0], acc[m][n], 0, 0, 0);
          acc[m][n] = __builtin_amdgcn_mfma_f32_16x16x32_bf16(avr[cur][m][1], bb[cur][n][1], acc[m][n], 0, 0, 0);
        }
      __builtin_amdgcn_s_setprio(0);
    }
    __syncthreads();                       // drains vmcnt: next buf ready; reads done
    if (cc < 3)                            // av0 of next cc (post-barrier: staging done)
      loadA(avr[(cc * 9 + 9) & 1], smem + ((cc + 1) & 1) * 24576, 0);
  }

  // ---- epilogue. C/D frag: col=l15, px_in_frag=k8*4+r (verified layout).
  if constexpr (FINAL) {
    constexpr int NCOL = NF * 32;
    constexpr int MASK = NCOL / 4 - 1;
    float* cf = (float*)smem;              // [64 px][NCOL co] fp32 per half
#pragma unroll
    for (int h = 0; h < 2; ++h) {
      if (h) __syncthreads();
      if ((wv & 1) == h) {
#pragma unroll
        for (int n = 0; n < NF; ++n) {
          const int col = (wv >> 1) * (NF * 16) + n * 16 + l15;
          const int colG = tileN + col;
          const float bvl = (colG < CoutReal) ? bias[colG] : 0.f;
          const int c32 = col >> 2;
#pragma unroll
          for (int m = 0; m < 4; ++m)
#pragma unroll
            for (int r = 0; r < 4; ++r) {
              const int pxl = m * 16 + (k8 << 2) + r;       // 0..63
              const int phys = (c32 + (k8 & 1) * 4) & MASK; // 2-way max
              cf[pxl * NCOL + phys * 4 + (col & 3)] = acc[m][n][r] + bvl;
            }
        }
      }
      __syncthreads();
#pragma unroll
      for (int it = 0; it < NCOL / 16; ++it) {
        const int q = it * 256 + tid;
        const int pxl = q / (NCOL / 4), c32 = q & MASK;
        const int colG = tileN + c32 * 4;
        if (colG < CoutReal) {
          const int phys = (c32 + ((pxl >> 2) & 1) * 4) & MASK;
          u32x4 v = *(const u32x4*)(cf + pxl * NCOL + phys * 4);
          const int px = h * 64 + pxl;
          const int y = ty + (px >> 4), x = tx + (px & 15);
          const size_t p = ((size_t)(n_img * H + y)) * W + x;
          *(u32x4*)(dstOut + p * CoutReal + colG) = v;
        }
      }
    }
  } else {
    unsigned short* cb = (unsigned short*)smem;   // [128 px][128 co] bf16 = 32 KB
#pragma unroll
    for (int n = 0; n < NF; ++n) {
      const int col = (wv >> 1) * (NF * 16) + n * 16 + l15;
      const float bvl = bias[tileN + col];
      const int c16 = col >> 3;
#pragma unroll
      for (int m = 0; m < 4; ++m)
#pragma unroll
        for (int r = 0; r < 4; ++r) {
          const int px = (wv & 1) * 64 + m * 16 + (k8 << 2) + r;
          const int phys = (c16 + k8 * 2) & 15;             // conflict-free
          cb[px * 128 + phys * 8 + (col & 7)] = f2bf(fmaxf(acc[m][n][r] + bvl, 0.f));
        }
    }
    __syncthreads();
#pragma unroll
    for (int it = 0; it < 8; ++it) {
      const int q = it * 256 + tid;
      const int px = q >> 4, c16 = q & 15;
      const int phys = (c16 + ((px >> 2) & 3) * 2) & 15;
      u32x4 v = *(const u32x4*)(cb + px * 128 + phys * 8);
      const int y = ty + (px >> 4), x = tx + (px & 15);
      const size_t o = ((size_t)(n_img * Hp + y + 1) * RL + x + 1) * 256 + tileN + c16 * 8;
      *(u32x4*)(dstAct + o) = v;
    }
  }
}

// ---------------------------------------------------------------- host
static void run_branch(const unsigned short* A, unsigned short* Am, unsigned short* B,
                       const unsigned short* wT, const float* bias,
                       const unsigned short* wTout, const float* biasOut,
                       bool cls, float* out, int H, int lntx, int lnty,
                       hipStream_t stream) {
  dim3 blk(256);
  const int np = 8 * (H / 16) * (H / 8);
  dim3 g1(np, 2);
  conv3x3_k<4, false><<<g1, blk, 0, stream>>>(A,  wT + 0L * 589824, bias + 0,   B,  nullptr, H, lntx, lnty, 256, 16);
  conv3x3_k<4, false><<<g1, blk, 0, stream>>>(B,  wT + 1L * 589824, bias + 256, Am, nullptr, H, lntx, lnty, 256, 16);
  conv3x3_k<4, false><<<g1, blk, 0, stream>>>(Am, wT + 2L * 589824, bias + 512, B,  nullptr, H, lntx, lnty, 256, 16);
  conv3x3_k<4, false><<<g1, blk, 0, stream>>>(B,  wT + 3L * 589824, bias + 768, Am, nullptr, H, lntx, lnty, 256, 16);
  if (cls) {
    dim3 g2(np, 6);
    conv3x3_k<4, true><<<g2, blk, 0, stream>>>(Am, wTout, biasOut, nullptr, out, H, lntx, lnty, 720, 48);
  } else {
    dim3 g2(np, 1);
    conv3x3_k<2, true><<<g2, blk, 0, stream>>>(Am, wTout, biasOut, nullptr, out, H, lntx, lnty, 36, 4);
  }
}

extern "C" void kernel_launch(void* const* d_in, const int* in_sizes, int n_in,
                              void* d_out, int out_size, void* d_ws, size_t ws_size,
                              hipStream_t stream) {
  const float* x[3] = {(const float*)d_in[0], (const float*)d_in[1], (const float*)d_in[2]};
  const float* cls_w      = (const float*)d_in[3];
  const float* cls_b      = (const float*)d_in[4];
  const float* bbox_w     = (const float*)d_in[5];
  const float* bbox_b     = (const float*)d_in[6];
  const float* cls_out_w  = (const float*)d_in[7];
  const float* cls_out_b  = (const float*)d_in[8];
  const float* bbox_out_w = (const float*)d_in[9];
  const float* bbox_out_b = (const float*)d_in[10];
  float* out = (float*)d_out;

  char* ws = (char*)d_ws;
  unsigned short* bufA = (unsigned short*)ws;
  unsigned short* bufB = (unsigned short*)(ws + 69222400);
  unsigned short* wt   = (unsigned short*)(ws + 138444800);
  unsigned short* wT_cls      = wt;
  unsigned short* wT_bbox     = wt + 4L * 589824;
  unsigned short* wT_cls_out  = wt + 8L * 589824;         // 36*48*2*512 = 1769472
  unsigned short* wT_bbox_out = wT_cls_out + 2211840;     // 36*4*2*512 = 147456

  for (int i = 0; i < 4; ++i) {
    conv_w_k<<<288, 256, 0, stream>>>(cls_w  + (long)i * 589824, wT_cls  + (long)i * 589824, 256, 16, 73728);
    conv_w_k<<<288, 256, 0, stream>>>(bbox_w + (long)i * 589824, wT_bbox + (long)i * 589824, 256, 16, 73728);
  }
  conv_w_k<<<864, 256, 0, stream>>>(cls_out_w,  wT_cls_out,  720, 48, 221184);
  conv_w_k<<<72, 256, 0, stream>>>(bbox_out_w, wT_bbox_out, 36, 4, 18432);

  const long clsOff[3] = {0L, 94371840L, 117964800L};
  const long boxOff[3] = {123863040L, 128581632L, 129761280L};
  const int Hs[3]    = {128, 64, 32};
  const int lntxs[3] = {3, 2, 1};
  const int lntys[3] = {4, 3, 2};

  for (int lv = 0; lv < 3; ++lv) {
    const int H = Hs[lv], Hp = H + 2;
    const int paddedElems = 8 * Hp * Hp * 256;
    const int totalConv = 8 * Hp * Hp * 32;

    zero_k<<<2048, 256, 0, stream>>>((u32x4*)bufB, paddedElems / 8);

    conv_in_k<<<(totalConv + 255) / 256, 256, 0, stream>>>(x[lv], bufA, H, totalConv);
    run_branch(bufA, bufA, bufB, wT_cls, cls_b, wT_cls_out, cls_out_b,
               true, out + clsOff[lv], H, lntxs[lv], lntys[lv], stream);

    conv_in_k<<<(totalConv + 255) / 256, 256, 0, stream>>>(x[lv], bufA, H, totalConv);
    run_branch(bufA, bufA, bufB, wT_bbox, bbox_b, wT_bbox_out, bbox_out_b,
               false, out + boxOff[lv], H, lntxs[lv], lntys[lv], stream);
  }
}

// Round 9
// 2039.558 us; speedup vs baseline: 4.9552x; 1.0157x over previous
//
#include <hip/hip_runtime.h>
#include <stdint.h>

typedef __attribute__((ext_vector_type(8))) short bf16x8;
typedef __attribute__((ext_vector_type(4))) float f32x4;
typedef __attribute__((ext_vector_type(4))) unsigned int u32x4;

__device__ __forceinline__ unsigned short f2bf(float f) {
  unsigned int u = __float_as_uint(f);
  return (unsigned short)((u + 0x7fffu + ((u >> 16) & 1u)) >> 16);  // RNE
}

__device__ __forceinline__ void gload16(const void* g, void* l) {
  __builtin_amdgcn_global_load_lds((const __attribute__((address_space(1))) void*)g,
                                   (__attribute__((address_space(3))) void*)l, 16, 0, 0);
}

// ---------------------------------------------------------------- zero
__global__ void zero_k(u32x4* __restrict__ p, int n16) {
  int i = blockIdx.x * blockDim.x + threadIdx.x;
  int stride = gridDim.x * blockDim.x;
  u32x4 z = {0u, 0u, 0u, 0u};
  for (; i < n16; i += stride) p[i] = z;
}

// ------------------------------------------- fp32 NHWC -> padded bf16 NHWC
__global__ void conv_in_k(const float* __restrict__ x, unsigned short* __restrict__ dst,
                          int H, int total) {
  int idx = blockIdx.x * 256 + threadIdx.x;
  if (idx >= total) return;
  const int W = H, Hp = H + 2, Wp = H + 2;
  int c8 = idx & 31;
  int rest = idx >> 5;
  int xp = rest % Wp;
  int r2 = rest / Wp;
  int yp = r2 % Hp;
  int n = r2 / Hp;
  u32x4 o = {0u, 0u, 0u, 0u};
  int iy = yp - 1, ix = xp - 1;
  if ((unsigned)iy < (unsigned)H && (unsigned)ix < (unsigned)W) {
    const float* s = x + ((long)((n * H + iy) * W + ix) * 256 + c8 * 8);
    float4 a = *(const float4*)s;
    float4 b = *(const float4*)(s + 4);
    o.x = f2bf(a.x) | ((unsigned)f2bf(a.y) << 16);
    o.y = f2bf(a.z) | ((unsigned)f2bf(a.w) << 16);
    o.z = f2bf(b.x) | ((unsigned)f2bf(b.y) << 16);
    o.w = f2bf(b.z) | ((unsigned)f2bf(b.w) << 16);
  }
  *(u32x4*)(dst + (long)idx * 8) = o;
}

// -------- HWIO fp32 -> bf16 MFMA-fragment layout (verified R2-R8)
// chunk f: l=f&63; ks=(f>>6)&1; jg=(f>>7)%NB; stage=(f>>7)/NB  (stage = tap*4+cc)
__global__ void conv_w_k(const float* __restrict__ w, unsigned short* __restrict__ wTf,
                         int CoutReal, int NB, int totalChunks) {
  int f = blockIdx.x * 256 + threadIdx.x;
  if (f >= totalChunks) return;
  int l = f & 63;
  int t2 = f >> 6;
  int ks = t2 & 1;
  int t3 = t2 >> 1;
  int jg = t3 % NB;
  int stage = t3 / NB;
  int col = jg * 16 + (l & 15);
  int kbase = stage * 64 + ks * 32 + ((l >> 4) << 3);
  u32x4 o = {0u, 0u, 0u, 0u};
  if (col < CoutReal) {
    unsigned short v[8];
#pragma unroll
    for (int e = 0; e < 8; ++e)
      v[e] = f2bf(w[(long)(kbase + e) * CoutReal + col]);
    o.x = v[0] | ((unsigned)v[1] << 16);
    o.y = v[2] | ((unsigned)v[3] << 16);
    o.z = v[4] | ((unsigned)v[5] << 16);
    o.w = v[6] | ((unsigned)v[7] << 16);
  }
  *(u32x4*)(wTf + (long)f * 8) = o;
}

// ---------------------------------------------------------------- conv 3x3
// Tile = 8x16 px patch (128 px) x NF*32 couts. 4 waves: wave = 64 px x NF*16 co.
// A: double-buffered LDS halo [10][18][64ch] per cc (T14 issue-early).
// Pipelining without extra registers: B = static ring-2 (parity s=cc*9+tap,
// full unroll, rule #20); A = IN-PLACE m-granular rotation: after the 8 MFMAs
// consuming avr[m] in tap t, avr[m] is re-loaded with tap t+1's fragment
// (WAR on same slots, ~200+ cy issue-to-consume). At cc boundary avr reloads
// after the barrier. T5 setprio wraps each tap's MFMA+rotate body.
template<int NF, bool FINAL>
__global__ __launch_bounds__(256, 2)
void conv3x3_k(const unsigned short* __restrict__ src,
               const unsigned short* __restrict__ wTf,
               const float* __restrict__ bias,
               unsigned short* __restrict__ dstAct,
               float* __restrict__ dstOut,
               int H, int lntx, int lnty, int CoutReal, int NB)
{
  __shared__ char smem[49152];   // A dbuf: [0,24576)+[24576,49152); epilogue reuses [0,32768)
  const int tid = threadIdx.x;
  const int W = H, Hp = H + 2, RL = H + 2;
  const int np = gridDim.x;
  const int bx = blockIdx.x;
  const int t = (bx & 7) * (np >> 3) + (bx >> 3);      // XCD-chunked swizzle
  const int tx = (t & ((1 << lntx) - 1)) << 4;
  const int ty = ((t >> lntx) & ((1 << lnty) - 1)) << 3;
  const int n_img = t >> (lntx + lnty);
  const int tileN = blockIdx.y * (NF * 32);

  // A staging: 180 halo rows (10y x 18x) x 128 B = 1440 chunks; 6 x 256 thr
  int srcOff[6];
#pragma unroll
  for (int j = 0; j < 6; ++j) {
    int q = j * 256 + tid;
    int hr = q >> 3, c = q & 7;
    if (hr >= 180) hr = 0;                 // tail dup, harmless
    int hy = hr / 18, hx = hr - hy * 18;
    int lch = c ^ (hr & 7);                // inverse swizzle on global source
    srcOff[j] = ((n_img * Hp + ty + hy) * RL + tx + hx) * 256 + lch * 8;
  }

  const int lane = tid & 63;
  const int wv = tid >> 6;
  const int l15 = lane & 15;
  const int k8 = lane >> 4;
  const int pxRow = (wv & 1) * 4;          // wave's first pixel row (of 8)
  const int jgBase = (tileN >> 4) + (wv >> 1) * NF;
  const unsigned short* wBp = wTf + (size_t)jgBase * 1024 + lane * 8;
  const size_t stageStride = (size_t)NB << 10;

  int rBase[4];
#pragma unroll
  for (int m = 0; m < 4; ++m)
    rBase[m] = (pxRow + m) * 18 + l15;

  f32x4 acc[4][NF];
#pragma unroll
  for (int m = 0; m < 4; ++m)
#pragma unroll
    for (int n = 0; n < NF; ++n)
      acc[m][n] = (f32x4){0.f, 0.f, 0.f, 0.f};

  auto loadB = [&](bf16x8 (&dst)[NF][2], int stage) {
    const unsigned short* bp = wBp + stage * stageStride;
#pragma unroll
    for (int n = 0; n < NF; ++n)
#pragma unroll
      for (int ks = 0; ks < 2; ++ks)
        dst[n][ks] = *(const bf16x8*)(bp + n * 1024 + ks * 512);
  };
  auto loadAm = [&](bf16x8 (&dst)[2], const char* buf, int tap, int m) {
    const int ky = tap / 3, kx = tap - ky * 3;
    const int rA = rBase[m] + ky * 18 + kx;
    const int a0 = rA * 128 + ((k8 ^ (rA & 7)) << 4);
    dst[0] = *(const bf16x8*)(buf + a0);
    dst[1] = *(const bf16x8*)(buf + (a0 ^ 64));
  };

  bf16x8 avr[4][2];                        // A fragments, in-place rotated
  bf16x8 bb[2][NF][2];                     // B static ring-2
  loadB(bb[0], 0);                         // stage (tap0, cc0)

  // prologue: stage cc=0 into buf0
#pragma unroll
  for (int j = 0; j < 6; ++j)
    gload16(src + srcOff[j], smem + j * 4096 + tid * 16);
  __syncthreads();
#pragma unroll
  for (int m = 0; m < 4; ++m)
    loadAm(avr[m], smem, 0, m);            // av for (cc0, tap0)

#pragma unroll
  for (int cc = 0; cc < 4; ++cc) {
    char* cbuf = smem + (cc & 1) * 24576;
    if (cc < 3) {                          // issue next A slice early (T14)
      char* nbuf = smem + ((cc + 1) & 1) * 24576;
#pragma unroll
      for (int j = 0; j < 6; ++j)
        gload16(src + srcOff[j] + (cc + 1) * 64, nbuf + j * 4096 + tid * 16);
    }
#pragma unroll
    for (int tap = 0; tap < 9; ++tap) {
      const int s = cc * 9 + tap;          // static ring parity for B
      const int cur = s & 1, nxt = cur ^ 1;
      if (cc < 3 || tap < 8)
        loadB(bb[nxt], (tap < 8) ? ((tap + 1) * 4 + cc) : (cc + 1));
      __builtin_amdgcn_s_setprio(1);       // T5
#pragma unroll
      for (int m = 0; m < 4; ++m) {
#pragma unroll
        for (int n = 0; n < NF; ++n) {
          acc[m][n] = __builtin_amdgcn_mfma_f32_16x16x32_bf16(avr[m][0], bb[cur][n][0], acc[m][n], 0, 0, 0);
          acc[m][n] = __builtin_amdgcn_mfma_f32_16x16x32_bf16(avr[m][1], bb[cur][n][1], acc[m][n], 0, 0, 0);
        }
        if (tap < 8)
          loadAm(avr[m], cbuf, tap + 1, m);   // in-place rotate: next tap's frag
      }
      __builtin_amdgcn_s_setprio(0);
    }
    __syncthreads();                       // drains vmcnt: next buf ready; reads done
    if (cc < 3) {                          // av tap0 of next cc (post-barrier)
      const char* nbuf = smem + ((cc + 1) & 1) * 24576;
#pragma unroll
      for (int m = 0; m < 4; ++m)
        loadAm(avr[m], nbuf, 0, m);
    }
  }

  // ---- epilogue. C/D frag: col=l15, px_in_frag=k8*4+r (verified layout).
  if constexpr (FINAL) {
    constexpr int NCOL = NF * 32;
    constexpr int MASK = NCOL / 4 - 1;
    float* cf = (float*)smem;              // [64 px][NCOL co] fp32 per half
#pragma unroll
    for (int h = 0; h < 2; ++h) {
      if (h) __syncthreads();
      if ((wv & 1) == h) {
#pragma unroll
        for (int n = 0; n < NF; ++n) {
          const int col = (wv >> 1) * (NF * 16) + n * 16 + l15;
          const int colG = tileN + col;
          const float bvl = (colG < CoutReal) ? bias[colG] : 0.f;
          const int c32 = col >> 2;
#pragma unroll
          for (int m = 0; m < 4; ++m)
#pragma unroll
            for (int r = 0; r < 4; ++r) {
              const int pxl = m * 16 + (k8 << 2) + r;       // 0..63
              const int phys = (c32 + (k8 & 1) * 4) & MASK; // 2-way max
              cf[pxl * NCOL + phys * 4 + (col & 3)] = acc[m][n][r] + bvl;
            }
        }
      }
      __syncthreads();
#pragma unroll
      for (int it = 0; it < NCOL / 16; ++it) {
        const int q = it * 256 + tid;
        const int pxl = q / (NCOL / 4), c32 = q & MASK;
        const int colG = tileN + c32 * 4;
        if (colG < CoutReal) {
          const int phys = (c32 + ((pxl >> 2) & 1) * 4) & MASK;
          u32x4 v = *(const u32x4*)(cf + pxl * NCOL + phys * 4);
          const int px = h * 64 + pxl;
          const int y = ty + (px >> 4), x = tx + (px & 15);
          const size_t p = ((size_t)(n_img * H + y)) * W + x;
          *(u32x4*)(dstOut + p * CoutReal + colG) = v;
        }
      }
    }
  } else {
    unsigned short* cb = (unsigned short*)smem;   // [128 px][128 co] bf16 = 32 KB
#pragma unroll
    for (int n = 0; n < NF; ++n) {
      const int col = (wv >> 1) * (NF * 16) + n * 16 + l15;
      const float bvl = bias[tileN + col];
      const int c16 = col >> 3;
#pragma unroll
      for (int m = 0; m < 4; ++m)
#pragma unroll
        for (int r = 0; r < 4; ++r) {
          const int px = (wv & 1) * 64 + m * 16 + (k8 << 2) + r;
          const int phys = (c16 + k8 * 2) & 15;             // conflict-free
          cb[px * 128 + phys * 8 + (col & 7)] = f2bf(fmaxf(acc[m][n][r] + bvl, 0.f));
        }
    }
    __syncthreads();
#pragma unroll
    for (int it = 0; it < 8; ++it) {
      const int q = it * 256 + tid;
      const int px = q >> 4, c16 = q & 15;
      const int phys = (c16 + ((px >> 2) & 3) * 2) & 15;
      u32x4 v = *(const u32x4*)(cb + px * 128 + phys * 8);
      const int y = ty + (px >> 4), x = tx + (px & 15);
      const size_t o = ((size_t)(n_img * Hp + y + 1) * RL + x + 1) * 256 + tileN + c16 * 8;
      *(u32x4*)(dstAct + o) = v;
    }
  }
}

// ---------------------------------------------------------------- host
static void run_branch(const unsigned short* A, unsigned short* Am, unsigned short* B,
                       const unsigned short* wT, const float* bias,
                       const unsigned short* wTout, const float* biasOut,
                       bool cls, float* out, int H, int lntx, int lnty,
                       hipStream_t stream) {
  dim3 blk(256);
  const int np = 8 * (H / 16) * (H / 8);
  dim3 g1(np, 2);
  conv3x3_k<4, false><<<g1, blk, 0, stream>>>(A,  wT + 0L * 589824, bias + 0,   B,  nullptr, H, lntx, lnty, 256, 16);
  conv3x3_k<4, false><<<g1, blk, 0, stream>>>(B,  wT + 1L * 589824, bias + 256, Am, nullptr, H, lntx, lnty, 256, 16);
  conv3x3_k<4, false><<<g1, blk, 0, stream>>>(Am, wT + 2L * 589824, bias + 512, B,  nullptr, H, lntx, lnty, 256, 16);
  conv3x3_k<4, false><<<g1, blk, 0, stream>>>(B,  wT + 3L * 589824, bias + 768, Am, nullptr, H, lntx, lnty, 256, 16);
  if (cls) {
    dim3 g2(np, 6);
    conv3x3_k<4, true><<<g2, blk, 0, stream>>>(Am, wTout, biasOut, nullptr, out, H, lntx, lnty, 720, 48);
  } else {
    dim3 g2(np, 1);
    conv3x3_k<2, true><<<g2, blk, 0, stream>>>(Am, wTout, biasOut, nullptr, out, H, lntx, lnty, 36, 4);
  }
}

extern "C" void kernel_launch(void* const* d_in, const int* in_sizes, int n_in,
                              void* d_out, int out_size, void* d_ws, size_t ws_size,
                              hipStream_t stream) {
  const float* x[3] = {(const float*)d_in[0], (const float*)d_in[1], (const float*)d_in[2]};
  const float* cls_w      = (const float*)d_in[3];
  const float* cls_b      = (const float*)d_in[4];
  const float* bbox_w     = (const float*)d_in[5];
  const float* bbox_b     = (const float*)d_in[6];
  const float* cls_out_w  = (const float*)d_in[7];
  const float* cls_out_b  = (const float*)d_in[8];
  const float* bbox_out_w = (const float*)d_in[9];
  const float* bbox_out_b = (const float*)d_in[10];
  float* out = (float*)d_out;

  char* ws = (char*)d_ws;
  unsigned short* bufA = (unsigned short*)ws;
  unsigned short* bufB = (unsigned short*)(ws + 69222400);
  unsigned short* wt   = (unsigned short*)(ws + 138444800);
  unsigned short* wT_cls      = wt;
  unsigned short* wT_bbox     = wt + 4L * 589824;
  unsigned short* wT_cls_out  = wt + 8L * 589824;         // 36*48*2*512 = 1769472
  unsigned short* wT_bbox_out = wT_cls_out + 2211840;     // 36*4*2*512 = 147456

  for (int i = 0; i < 4; ++i) {
    conv_w_k<<<288, 256, 0, stream>>>(cls_w  + (long)i * 589824, wT_cls  + (long)i * 589824, 256, 16, 73728);
    conv_w_k<<<288, 256, 0, stream>>>(bbox_w + (long)i * 589824, wT_bbox + (long)i * 589824, 256, 16, 73728);
  }
  conv_w_k<<<864, 256, 0, stream>>>(cls_out_w,  wT_cls_out,  720, 48, 221184);
  conv_w_k<<<72, 256, 0, stream>>>(bbox_out_w, wT_bbox_out, 36, 4, 18432);

  const long clsOff[3] = {0L, 94371840L, 117964800L};
  const long boxOff[3] = {123863040L, 128581632L, 129761280L};
  const int Hs[3]    = {128, 64, 32};
  const int lntxs[3] = {3, 2, 1};
  const int lntys[3] = {4, 3, 2};

  for (int lv = 0; lv < 3; ++lv) {
    const int H = Hs[lv], Hp = H + 2;
    const int paddedElems = 8 * Hp * Hp * 256;
    const int totalConv = 8 * Hp * Hp * 32;

    zero_k<<<2048, 256, 0, stream>>>((u32x4*)bufB, paddedElems / 8);

    conv_in_k<<<(totalConv + 255) / 256, 256, 0, stream>>>(x[lv], bufA, H, totalConv);
    run_branch(bufA, bufA, bufB, wT_cls, cls_b, wT_cls_out, cls_out_b,
               true, out + clsOff[lv], H, lntxs[lv], lntys[lv], stream);

    conv_in_k<<<(totalConv + 255) / 256, 256, 0, stream>>>(x[lv], bufA, H, totalConv);
    run_branch(bufA, bufA, bufB, wT_bbox, bbox_b, wT_bbox_out, bbox_out_b,
               false, out + boxOff[lv], H, lntxs[lv], lntys[lv], stream);
  }
}